// Round 1
// baseline (4441.696 us; speedup 1.0000x reference)
//
#include <hip/hip_runtime.h>
#include <hip/hip_bf16.h>
#include <cstddef>

// Mamba2 (2 layers), fp32 throughout.
// Shapes: B=4, L=2048, D_MODEL=512, D_INNER=1024, D_STATE=128, HEADDIM=64,
// NHEADS=16, D_CONV=4, CONV_DIM=1280, D_IN_PROJ=2320.
//
// Pipeline per layer:
//   1) gemm_f32: zx = x @ in_w                      (8192 x 2320, K=512)
//   2) conv_silu: depthwise conv(4 taps)+bias+SiLU -> xh/B/C ; dt->softplus, dA=exp(-a*dt)
//   3) scan: 256 blocks (b,h,n-quarter) x 1 wave; state in regs; writes 4 y-partials
//   4) gate+rmsnorm: y=sum(partials); y*=silu(z); RMSNorm*norm_w -> overlay into zx cols [1024,2048)
//   5) gemm_f32: out = ynorm @ out_w                (8192 x 512, K=1024)
//
// Workspace layout (floats): zx 19,005,440 | xh 8,388,608 | Bb 1,048,576 |
// Cb 1,048,576 | dtb 131,072 | dAb 131,072 | ypart 33,554,432  => ~253 MB total.

#define BATCH 4
#define SEQ   2048
#define DMODEL 512
#define DINNER 1024
#define DSTATE 128
#define HEADDIM 64
#define NHEADS 16
#define DCONV 4
#define CONVDIM 1280
#define DINPROJ 2320
#define ROWS (BATCH * SEQ)   // 8192

__device__ __forceinline__ float silu_f(float x) {
    return x * (1.0f / (1.0f + __expf(-x)));
}

// ---------------------------------------------------------------------------
// fp32 GEMM: C[M,N] = A[M,K] @ B[K,N], row-major, arbitrary lda/ldb/ldc.
// 128x128 tile, BK=16, 256 threads, 8x8 micro-tile (2x2 blocks of 4x4).
// M must be a multiple of 128, K a multiple of 16; N guarded (mult of 4).
// ---------------------------------------------------------------------------
__global__ __launch_bounds__(256)
void gemm_f32(const float* __restrict__ A, int lda,
              const float* __restrict__ B, int ldb,
              float* __restrict__ C, int ldc,
              int N, int K)
{
    __shared__ float As[16][132];
    __shared__ float Bs[16][132];

    const int tid = threadIdx.x;
    const int tx  = tid & 15;
    const int ty  = tid >> 4;
    const int row0 = blockIdx.y * 128;
    const int col0 = blockIdx.x * 128;

    const int arow = tid >> 2;           // 0..63
    const int ak   = (tid & 3) * 4;      // 0,4,8,12
    const int bk   = tid >> 5;           // 0..7
    const int bc   = (tid & 31) * 4;     // 0..124

    float acc[8][8];
#pragma unroll
    for (int i = 0; i < 8; ++i)
#pragma unroll
        for (int j = 0; j < 8; ++j) acc[i][j] = 0.0f;

    const bool bvalid = (col0 + bc) < N;

    for (int k0 = 0; k0 < K; k0 += 16) {
        const float4 a0 = *(const float4*)&A[(size_t)(row0 + arow) * lda + k0 + ak];
        const float4 a1 = *(const float4*)&A[(size_t)(row0 + arow + 64) * lda + k0 + ak];
        float4 b0 = make_float4(0.f, 0.f, 0.f, 0.f);
        float4 b1 = make_float4(0.f, 0.f, 0.f, 0.f);
        if (bvalid) {
            b0 = *(const float4*)&B[(size_t)(k0 + bk) * ldb + col0 + bc];
            b1 = *(const float4*)&B[(size_t)(k0 + bk + 8) * ldb + col0 + bc];
        }
        As[ak + 0][arow] = a0.x;
        As[ak + 1][arow] = a0.y;
        As[ak + 2][arow] = a0.z;
        As[ak + 3][arow] = a0.w;
        As[ak + 0][arow + 64] = a1.x;
        As[ak + 1][arow + 64] = a1.y;
        As[ak + 2][arow + 64] = a1.z;
        As[ak + 3][arow + 64] = a1.w;
        *(float4*)&Bs[bk][bc]     = b0;
        *(float4*)&Bs[bk + 8][bc] = b1;
        __syncthreads();

#pragma unroll
        for (int k = 0; k < 16; ++k) {
            const float4 av0 = *(const float4*)&As[k][ty * 4];
            const float4 av1 = *(const float4*)&As[k][ty * 4 + 64];
            const float4 bv0 = *(const float4*)&Bs[k][tx * 4];
            const float4 bv1 = *(const float4*)&Bs[k][tx * 4 + 64];
            const float ar[8] = {av0.x, av0.y, av0.z, av0.w, av1.x, av1.y, av1.z, av1.w};
            const float br[8] = {bv0.x, bv0.y, bv0.z, bv0.w, bv1.x, bv1.y, bv1.z, bv1.w};
#pragma unroll
            for (int i = 0; i < 8; ++i)
#pragma unroll
                for (int j = 0; j < 8; ++j)
                    acc[i][j] = fmaf(ar[i], br[j], acc[i][j]);
        }
        __syncthreads();
    }

#pragma unroll
    for (int i = 0; i < 8; ++i) {
        const int r = row0 + ty * 4 + (i & 3) + (i >> 2) * 64;
#pragma unroll
        for (int jj = 0; jj < 2; ++jj) {
            const int c = col0 + tx * 4 + jj * 64;
            if (c < N) {
                float4 o = make_float4(acc[i][jj * 4 + 0], acc[i][jj * 4 + 1],
                                       acc[i][jj * 4 + 2], acc[i][jj * 4 + 3]);
                *(float4*)&C[(size_t)r * ldc + c] = o;
            }
        }
    }
}

// ---------------------------------------------------------------------------
// Depthwise causal conv (4 taps) + bias + SiLU over the xBC slice of zx,
// plus dt -> softplus(dt+bias), dA = exp(-exp(A_log)*dt).
// grid = 8192 rows, block = 320 threads (4 channels each).
// ---------------------------------------------------------------------------
__global__ __launch_bounds__(320)
void conv_kernel(const float* __restrict__ zx,
                 const float* __restrict__ cw,   // (4,1280)
                 const float* __restrict__ cb,   // (1280)
                 const float* __restrict__ dtbias, // (16)
                 const float* __restrict__ alog,   // (16)
                 float* __restrict__ xh,   // (rows,1024)
                 float* __restrict__ Bb,   // (rows,128)
                 float* __restrict__ Cb,   // (rows,128)
                 float* __restrict__ dtb,  // (rows,16)
                 float* __restrict__ dAb)  // (rows,16)
{
    const int row = blockIdx.x;          // b*SEQ + l
    const int l   = row & (SEQ - 1);
    const int c4  = threadIdx.x * 4;

    float4 acc = *(const float4*)&cb[c4];
#pragma unroll
    for (int k = 0; k < DCONV; ++k) {
        const int lk = l - (DCONV - 1) + k;
        if (lk >= 0) {
            const float4 v = *(const float4*)&zx[(size_t)(row - (DCONV - 1) + k) * DINPROJ + DINNER + c4];
            const float4 w = *(const float4*)&cw[k * CONVDIM + c4];
            acc.x = fmaf(v.x, w.x, acc.x);
            acc.y = fmaf(v.y, w.y, acc.y);
            acc.z = fmaf(v.z, w.z, acc.z);
            acc.w = fmaf(v.w, w.w, acc.w);
        }
    }
    acc.x = silu_f(acc.x);
    acc.y = silu_f(acc.y);
    acc.z = silu_f(acc.z);
    acc.w = silu_f(acc.w);

    if (c4 < DINNER) {
        *(float4*)&xh[(size_t)row * DINNER + c4] = acc;
    } else if (c4 < DINNER + DSTATE) {
        *(float4*)&Bb[(size_t)row * DSTATE + (c4 - DINNER)] = acc;
    } else {
        *(float4*)&Cb[(size_t)row * DSTATE + (c4 - DINNER - DSTATE)] = acc;
    }

    if (threadIdx.x < NHEADS) {
        const int hh = threadIdx.x;
        const float raw = zx[(size_t)row * DINPROJ + (DINNER + CONVDIM) + hh] + dtbias[hh];
        const float dtv = (raw > 20.0f) ? raw : log1pf(expf(raw));
        const float a = expf(alog[hh]);
        dtb[row * NHEADS + hh] = dtv;
        dAb[row * NHEADS + hh] = expf(-a * dtv);
    }
}

// ---------------------------------------------------------------------------
// Selective scan. grid = 256 blocks: (b, h, q) with q = n-quarter (32 states).
// block = 64 threads; lane = p. State hs[32] in registers. Double-buffered
// wave-uniform B/C (+ dA/dt/x) prefetch one step ahead to hide latency.
// Writes y-partials (q, b, l, h, p); q==0 also adds D_skip * x.
// ---------------------------------------------------------------------------
__device__ __forceinline__ void scan_prefetch(const float* __restrict__ Bt,
                                              const float* __restrict__ Ct,
                                              float (&bv)[32], float (&cv)[32])
{
#pragma unroll
    for (int j = 0; j < 32; ++j) {
        bv[j] = Bt[j];
        cv[j] = Ct[j];
    }
}

__device__ __forceinline__ void scan_step(float (&hs)[32], float dA, float dtx,
                                          const float (&bv)[32], const float (&cv)[32],
                                          float& y)
{
#pragma unroll
    for (int j = 0; j < 32; ++j) {
        hs[j] = fmaf(dA, hs[j], dtx * bv[j]);
        y = fmaf(hs[j], cv[j], y);
    }
}

__global__ __launch_bounds__(64)
void scan_kernel(const float* __restrict__ xh,
                 const float* __restrict__ Bb,
                 const float* __restrict__ Cb,
                 const float* __restrict__ dtb,
                 const float* __restrict__ dAb,
                 const float* __restrict__ dskip, // (16)
                 float* __restrict__ yp)          // (4, rows, 1024)
{
    const int bid = blockIdx.x;
    const int b = bid >> 6;
    const int h = (bid >> 2) & 15;
    const int q = bid & 3;
    const int n0 = q * 32;
    const int lane = threadIdx.x;

    float hs[32];
#pragma unroll
    for (int j = 0; j < 32; ++j) hs[j] = 0.0f;

    const float dsk = dskip[h];
    const size_t rowbase = (size_t)b * SEQ;

    const float* __restrict__ Bbase = Bb + n0;
    const float* __restrict__ Cbase = Cb + n0;

    float bv0[32], cv0[32], bv1[32], cv1[32];

    // preload t=0
    size_t r = rowbase;
    float dA0 = dAb[r * NHEADS + h];
    float dt0 = dtb[r * NHEADS + h];
    float xv0 = xh[r * DINNER + h * HEADDIM + lane];
    scan_prefetch(Bbase + r * DSTATE, Cbase + r * DSTATE, bv0, cv0);

    for (int t = 0; t < SEQ; t += 2) {
        // prefetch t+1
        const size_t r1 = rowbase + t + 1;
        const float dA1 = dAb[r1 * NHEADS + h];
        const float dt1 = dtb[r1 * NHEADS + h];
        const float xv1 = xh[r1 * DINNER + h * HEADDIM + lane];
        scan_prefetch(Bbase + r1 * DSTATE, Cbase + r1 * DSTATE, bv1, cv1);

        // compute t
        {
            float y = (q == 0) ? dsk * xv0 : 0.0f;
            scan_step(hs, dA0, dt0 * xv0, bv0, cv0, y);
            yp[((size_t)q * ROWS + rowbase + t) * DINNER + h * HEADDIM + lane] = y;
        }

        // prefetch t+2 (clamped)
        const int t2 = (t + 2 < SEQ) ? (t + 2) : (SEQ - 1);
        const size_t r2 = rowbase + t2;
        dA0 = dAb[r2 * NHEADS + h];
        dt0 = dtb[r2 * NHEADS + h];
        xv0 = xh[r2 * DINNER + h * HEADDIM + lane];
        scan_prefetch(Bbase + r2 * DSTATE, Cbase + r2 * DSTATE, bv0, cv0);

        // compute t+1
        {
            float y = (q == 0) ? dsk * xv1 : 0.0f;
            scan_step(hs, dA1, dt1 * xv1, bv1, cv1, y);
            yp[((size_t)q * ROWS + r1) * DINNER + h * HEADDIM + lane] = y;
        }
    }
}

// ---------------------------------------------------------------------------
// y = sum_q ypart; y *= silu(z); RMSNorm over 1024; * norm_w.
// Writes result into zx columns [1024, 2048) (row stride 2320) so the
// output GEMM can read it with lda=2320.
// grid = 8192 rows, block = 256 (4 channels/thread).
// ---------------------------------------------------------------------------
__global__ __launch_bounds__(256)
void gate_kernel(const float* __restrict__ yp,
                 float* __restrict__ zx,
                 const float* __restrict__ nw) // (1024)
{
    const int row = blockIdx.x;
    const int c4 = threadIdx.x * 4;

    float4 y = *(const float4*)&yp[((size_t)0 * ROWS + row) * DINNER + c4];
#pragma unroll
    for (int q = 1; q < 4; ++q) {
        const float4 t = *(const float4*)&yp[((size_t)q * ROWS + row) * DINNER + c4];
        y.x += t.x; y.y += t.y; y.z += t.z; y.w += t.w;
    }

    const float4 z = *(const float4*)&zx[(size_t)row * DINPROJ + c4];
    float4 g;
    g.x = y.x * silu_f(z.x);
    g.y = y.y * silu_f(z.y);
    g.z = y.z * silu_f(z.z);
    g.w = y.w * silu_f(z.w);

    float local = g.x * g.x + g.y * g.y + g.z * g.z + g.w * g.w;
#pragma unroll
    for (int m = 32; m >= 1; m >>= 1) local += __shfl_xor(local, m, 64);

    __shared__ float red[4];
    if ((threadIdx.x & 63) == 0) red[threadIdx.x >> 6] = local;
    __syncthreads();
    const float total = red[0] + red[1] + red[2] + red[3];
    const float scale = rsqrtf(total * (1.0f / (float)DINNER) + 1e-5f);

    const float4 w = *(const float4*)&nw[c4];
    float4 o;
    o.x = g.x * scale * w.x;
    o.y = g.y * scale * w.y;
    o.z = g.z * scale * w.z;
    o.w = g.w * scale * w.w;
    *(float4*)&zx[(size_t)row * DINPROJ + DINNER + c4] = o;
}

// ---------------------------------------------------------------------------
extern "C" void kernel_launch(void* const* d_in, const int* in_sizes, int n_in,
                              void* d_out, int out_size, void* d_ws, size_t ws_size,
                              hipStream_t stream)
{
    const float* x_in    = (const float*)d_in[0];
    const float* in_w    = (const float*)d_in[1];
    const float* conv_w  = (const float*)d_in[2];
    const float* conv_b  = (const float*)d_in[3];
    const float* dt_bias = (const float*)d_in[4];
    const float* A_log   = (const float*)d_in[5];
    const float* D_skip  = (const float*)d_in[6];
    const float* norm_w  = (const float*)d_in[7];
    const float* out_w   = (const float*)d_in[8];
    float* out = (float*)d_out;

    float* ws  = (float*)d_ws;
    float* zx  = ws;                              // 8192*2320 = 19,005,440
    float* xh  = zx  + (size_t)ROWS * DINPROJ;    // 8192*1024
    float* Bb  = xh  + (size_t)ROWS * DINNER;     // 8192*128
    float* Cb  = Bb  + (size_t)ROWS * DSTATE;     // 8192*128
    float* dtb = Cb  + (size_t)ROWS * DSTATE;     // 8192*16
    float* dAb = dtb + (size_t)ROWS * NHEADS;     // 8192*16
    float* yp  = dAb + (size_t)ROWS * NHEADS;     // 4*8192*1024

    for (int layer = 0; layer < 2; ++layer) {
        const float* xl = (layer == 0) ? x_in : out;

        // 1) zx = x @ in_w   (M=8192, N=2320, K=512)
        gemm_f32<<<dim3((DINPROJ + 127) / 128, ROWS / 128), 256, 0, stream>>>(
            xl, DMODEL,
            in_w + (size_t)layer * DMODEL * DINPROJ, DINPROJ,
            zx, DINPROJ,
            DINPROJ, DMODEL);

        // 2) conv + silu + dt/dA
        conv_kernel<<<ROWS, CONVDIM / 4, 0, stream>>>(
            zx,
            conv_w + (size_t)layer * DCONV * CONVDIM,
            conv_b + (size_t)layer * CONVDIM,
            dt_bias + (size_t)layer * NHEADS,
            A_log + (size_t)layer * NHEADS,
            xh, Bb, Cb, dtb, dAb);

        // 3) scan
        scan_kernel<<<BATCH * NHEADS * 4, 64, 0, stream>>>(
            xh, Bb, Cb, dtb, dAb,
            D_skip + (size_t)layer * NHEADS, yp);

        // 4) gate + rmsnorm (writes into zx cols [1024,2048))
        gate_kernel<<<ROWS, 256, 0, stream>>>(
            yp, zx, norm_w + (size_t)layer * DINNER);

        // 5) out = ynorm @ out_w   (M=8192, N=512, K=1024)
        gemm_f32<<<dim3(DMODEL / 128, ROWS / 128), 256, 0, stream>>>(
            zx + DINNER, DINPROJ,
            out_w + (size_t)layer * DINNER * DMODEL, DMODEL,
            out, DMODEL,
            DMODEL, DINNER);
    }
}

// Round 3
// 1449.619 us; speedup vs baseline: 3.0640x; 3.0640x over previous
//
#include <hip/hip_runtime.h>
#include <hip/hip_bf16.h>
#include <cstddef>

// Mamba2 (2 layers), fp32. Segmented-parallel selective scan, full-state waves.
// B=4, L=2048, D_MODEL=512, D_INNER=1024, D_STATE=128, HEADDIM=64, NHEADS=16,
// D_CONV=4, CONV_DIM=1280, D_IN_PROJ=2320.  NSEG=32 segments x TSEG=64 steps.
//
// Scan decomposition: one wave per (b,h,seg); lane = p (64 lanes); each lane
// holds all 128 n-states in registers -> y is lane-local (no partials).
//   scan_local: h0=0, 64 steps, write end-state (128x64) + Ptot=prod(dA)
//   combine:    sequential over 32 segs -> true h0 per seg (in-place, exact)
//   scan_full:  init from h0, recompute scan, write y directly
//
// Workspace (floats): zx 19.0M | xh 8.4M | Bb 1.05M | Cb 1.05M | dtb 0.13M |
// dAb 0.13M | y 8.4M | hloc 16.8M | ptot 2k  => ~220 MB (budget ~256 MB).

#define BATCH 4
#define SEQ   2048
#define DMODEL 512
#define DINNER 1024
#define DSTATE 128
#define HEADDIM 64
#define NHEADS 16
#define DCONV 4
#define CONVDIM 1280
#define DINPROJ 2320
#define ROWS (BATCH * SEQ)   // 8192
#define NSEG 32
#define TSEG 64              // SEQ / NSEG

__device__ __forceinline__ float silu_f(float x) {
    return x * (1.0f / (1.0f + __expf(-x)));
}

// ---------------------------------------------------------------------------
// fp32 GEMM: C[M,N] = A[M,K] @ B[K,N], row-major. 128x128 tile, BK=16,
// 256 threads, 8x8 micro-tile. (unchanged from passing round 1)
// ---------------------------------------------------------------------------
__global__ __launch_bounds__(256)
void gemm_f32(const float* __restrict__ A, int lda,
              const float* __restrict__ B, int ldb,
              float* __restrict__ C, int ldc,
              int N, int K)
{
    __shared__ float As[16][132];
    __shared__ float Bs[16][132];

    const int tid = threadIdx.x;
    const int tx  = tid & 15;
    const int ty  = tid >> 4;
    const int row0 = blockIdx.y * 128;
    const int col0 = blockIdx.x * 128;

    const int arow = tid >> 2;           // 0..63
    const int ak   = (tid & 3) * 4;      // 0,4,8,12
    const int bk   = tid >> 5;           // 0..7
    const int bc   = (tid & 31) * 4;     // 0..124

    float acc[8][8];
#pragma unroll
    for (int i = 0; i < 8; ++i)
#pragma unroll
        for (int j = 0; j < 8; ++j) acc[i][j] = 0.0f;

    const bool bvalid = (col0 + bc) < N;

    for (int k0 = 0; k0 < K; k0 += 16) {
        const float4 a0 = *(const float4*)&A[(size_t)(row0 + arow) * lda + k0 + ak];
        const float4 a1 = *(const float4*)&A[(size_t)(row0 + arow + 64) * lda + k0 + ak];
        float4 b0 = make_float4(0.f, 0.f, 0.f, 0.f);
        float4 b1 = make_float4(0.f, 0.f, 0.f, 0.f);
        if (bvalid) {
            b0 = *(const float4*)&B[(size_t)(k0 + bk) * ldb + col0 + bc];
            b1 = *(const float4*)&B[(size_t)(k0 + bk + 8) * ldb + col0 + bc];
        }
        As[ak + 0][arow] = a0.x;
        As[ak + 1][arow] = a0.y;
        As[ak + 2][arow] = a0.z;
        As[ak + 3][arow] = a0.w;
        As[ak + 0][arow + 64] = a1.x;
        As[ak + 1][arow + 64] = a1.y;
        As[ak + 2][arow + 64] = a1.z;
        As[ak + 3][arow + 64] = a1.w;
        *(float4*)&Bs[bk][bc]     = b0;
        *(float4*)&Bs[bk + 8][bc] = b1;
        __syncthreads();

#pragma unroll
        for (int k = 0; k < 16; ++k) {
            const float4 av0 = *(const float4*)&As[k][ty * 4];
            const float4 av1 = *(const float4*)&As[k][ty * 4 + 64];
            const float4 bv0 = *(const float4*)&Bs[k][tx * 4];
            const float4 bv1 = *(const float4*)&Bs[k][tx * 4 + 64];
            const float ar[8] = {av0.x, av0.y, av0.z, av0.w, av1.x, av1.y, av1.z, av1.w};
            const float br[8] = {bv0.x, bv0.y, bv0.z, bv0.w, bv1.x, bv1.y, bv1.z, bv1.w};
#pragma unroll
            for (int i = 0; i < 8; ++i)
#pragma unroll
                for (int j = 0; j < 8; ++j)
                    acc[i][j] = fmaf(ar[i], br[j], acc[i][j]);
        }
        __syncthreads();
    }

#pragma unroll
    for (int i = 0; i < 8; ++i) {
        const int r = row0 + ty * 4 + (i & 3) + (i >> 2) * 64;
#pragma unroll
        for (int jj = 0; jj < 2; ++jj) {
            const int c = col0 + tx * 4 + jj * 64;
            if (c < N) {
                float4 o = make_float4(acc[i][jj * 4 + 0], acc[i][jj * 4 + 1],
                                       acc[i][jj * 4 + 2], acc[i][jj * 4 + 3]);
                *(float4*)&C[(size_t)r * ldc + c] = o;
            }
        }
    }
}

// ---------------------------------------------------------------------------
// Depthwise causal conv (4 taps) + bias + SiLU + dt/dA precompute.
// ---------------------------------------------------------------------------
__global__ __launch_bounds__(320)
void conv_kernel(const float* __restrict__ zx,
                 const float* __restrict__ cw,
                 const float* __restrict__ cb,
                 const float* __restrict__ dtbias,
                 const float* __restrict__ alog,
                 float* __restrict__ xh,
                 float* __restrict__ Bb,
                 float* __restrict__ Cb,
                 float* __restrict__ dtb,
                 float* __restrict__ dAb)
{
    const int row = blockIdx.x;
    const int l   = row & (SEQ - 1);
    const int c4  = threadIdx.x * 4;

    float4 acc = *(const float4*)&cb[c4];
#pragma unroll
    for (int k = 0; k < DCONV; ++k) {
        const int lk = l - (DCONV - 1) + k;
        if (lk >= 0) {
            const float4 v = *(const float4*)&zx[(size_t)(row - (DCONV - 1) + k) * DINPROJ + DINNER + c4];
            const float4 w = *(const float4*)&cw[k * CONVDIM + c4];
            acc.x = fmaf(v.x, w.x, acc.x);
            acc.y = fmaf(v.y, w.y, acc.y);
            acc.z = fmaf(v.z, w.z, acc.z);
            acc.w = fmaf(v.w, w.w, acc.w);
        }
    }
    acc.x = silu_f(acc.x);
    acc.y = silu_f(acc.y);
    acc.z = silu_f(acc.z);
    acc.w = silu_f(acc.w);

    if (c4 < DINNER) {
        *(float4*)&xh[(size_t)row * DINNER + c4] = acc;
    } else if (c4 < DINNER + DSTATE) {
        *(float4*)&Bb[(size_t)row * DSTATE + (c4 - DINNER)] = acc;
    } else {
        *(float4*)&Cb[(size_t)row * DSTATE + (c4 - DINNER - DSTATE)] = acc;
    }

    if (threadIdx.x < NHEADS) {
        const int hh = threadIdx.x;
        const float raw = zx[(size_t)row * DINPROJ + (DINNER + CONVDIM) + hh] + dtbias[hh];
        const float dtv = (raw > 20.0f) ? raw : log1pf(expf(raw));
        const float a = expf(alog[hh]);
        dtb[row * NHEADS + hh] = dtv;
        dAb[row * NHEADS + hh] = expf(-a * dtv);
    }
}

// ---------------------------------------------------------------------------
// Pass 1: local scan per segment, h0 = 0, state-only.
// grid = b*h*seg = 2048 blocks x 64 threads; lane = p, hs[128] in regs.
// ---------------------------------------------------------------------------
__global__ __launch_bounds__(64, 2)
void scan_local(const float* __restrict__ xh,
                const float* __restrict__ Bb,
                const float* __restrict__ dtb,
                const float* __restrict__ dAb,
                float* __restrict__ hloc,   // (b,h,seg) x (128n x 64p)
                float* __restrict__ ptot)   // (b,h,seg)
{
    const int bid = blockIdx.x;
    const int seg = bid & (NSEG - 1);
    const int h   = (bid >> 5) & (NHEADS - 1);
    const int b   = bid >> 9;
    const int lane = threadIdx.x;

    float hs[DSTATE];
#pragma unroll
    for (int j = 0; j < DSTATE; ++j) hs[j] = 0.0f;
    float prun = 1.0f;

    const size_t row0 = (size_t)b * SEQ + (size_t)seg * TSEG;
    const float* __restrict__ Bp  = Bb  + row0 * DSTATE;
    const float* __restrict__ xp  = xh  + row0 * DINNER + h * HEADDIM + lane;
    const float* __restrict__ dAp = dAb + row0 * NHEADS + h;
    const float* __restrict__ dtp = dtb + row0 * NHEADS + h;

    for (int t = 0; t < TSEG; ++t) {
        const float dA  = dAp[t * NHEADS];
        const float dtx = dtp[t * NHEADS] * xp[(size_t)t * DINNER];
        prun *= dA;
#pragma unroll
        for (int j4 = 0; j4 < DSTATE / 4; ++j4) {
            const float4 b4 = *(const float4*)&Bp[(size_t)t * DSTATE + j4 * 4];
            hs[j4 * 4 + 0] = fmaf(dA, hs[j4 * 4 + 0], dtx * b4.x);
            hs[j4 * 4 + 1] = fmaf(dA, hs[j4 * 4 + 1], dtx * b4.y);
            hs[j4 * 4 + 2] = fmaf(dA, hs[j4 * 4 + 2], dtx * b4.z);
            hs[j4 * 4 + 3] = fmaf(dA, hs[j4 * 4 + 3], dtx * b4.w);
        }
    }

    const size_t sidx = (size_t)((b * NHEADS + h) * NSEG + seg) * (DSTATE * HEADDIM);
#pragma unroll
    for (int j = 0; j < DSTATE; ++j)
        hloc[sidx + (size_t)j * HEADDIM + lane] = hs[j];
    if (lane == 0)
        ptot[(b * NHEADS + h) * NSEG + seg] = prun;
}

// ---------------------------------------------------------------------------
// Pass 2: sequential combine over 32 segments (in-place: hloc becomes h0).
// h0_k = s; s = Ptot_k * s + hloc_k.  grid = 64 bh * 8 chunks, 256 thr.
// ---------------------------------------------------------------------------
__global__ __launch_bounds__(256)
void combine_kernel(float* __restrict__ hloc,
                    const float* __restrict__ ptot)
{
    const int bid = blockIdx.x;
    const int bh = bid >> 3;
    const int chunk = bid & 7;
    const int e0 = chunk * 1024 + threadIdx.x * 4;

    float4 s = make_float4(0.f, 0.f, 0.f, 0.f);
    for (int k = 0; k < NSEG; ++k) {
        float* p = &hloc[((size_t)bh * NSEG + k) * (DSTATE * HEADDIM) + e0];
        const float4 v = *(const float4*)p;
        *(float4*)p = s;
        const float pt = ptot[bh * NSEG + k];
        s.x = fmaf(pt, s.x, v.x);
        s.y = fmaf(pt, s.y, v.y);
        s.z = fmaf(pt, s.z, v.z);
        s.w = fmaf(pt, s.w, v.w);
    }
}

// ---------------------------------------------------------------------------
// Pass 3: full scan per segment with true h0; writes y directly.
// grid = 2048 blocks x 64 threads; lane = p, hs[128] in regs, y lane-local.
// ---------------------------------------------------------------------------
__global__ __launch_bounds__(64, 2)
void scan_full(const float* __restrict__ xh,
               const float* __restrict__ Bb,
               const float* __restrict__ Cb,
               const float* __restrict__ dtb,
               const float* __restrict__ dAb,
               const float* __restrict__ h0,    // (b,h,seg) x (128n x 64p)
               const float* __restrict__ dskip, // (16)
               float* __restrict__ yb)          // (rows, 1024)
{
    const int bid = blockIdx.x;
    const int seg = bid & (NSEG - 1);
    const int h   = (bid >> 5) & (NHEADS - 1);
    const int b   = bid >> 9;
    const int lane = threadIdx.x;

    const size_t sidx = (size_t)((b * NHEADS + h) * NSEG + seg) * (DSTATE * HEADDIM);
    float hs[DSTATE];
#pragma unroll
    for (int j = 0; j < DSTATE; ++j)
        hs[j] = h0[sidx + (size_t)j * HEADDIM + lane];

    const float dsk = dskip[h];
    const size_t row0 = (size_t)b * SEQ + (size_t)seg * TSEG;
    const float* __restrict__ Bp  = Bb  + row0 * DSTATE;
    const float* __restrict__ Cp  = Cb  + row0 * DSTATE;
    const float* __restrict__ xp  = xh  + row0 * DINNER + h * HEADDIM + lane;
    const float* __restrict__ dAp = dAb + row0 * NHEADS + h;
    const float* __restrict__ dtp = dtb + row0 * NHEADS + h;
    float* __restrict__ yo = yb + row0 * DINNER + h * HEADDIM + lane;

    for (int t = 0; t < TSEG; ++t) {
        const float dA  = dAp[t * NHEADS];
        const float xv  = xp[(size_t)t * DINNER];
        const float dtx = dtp[t * NHEADS] * xv;
        float y = dsk * xv;
#pragma unroll
        for (int j4 = 0; j4 < DSTATE / 4; ++j4) {
            const float4 b4 = *(const float4*)&Bp[(size_t)t * DSTATE + j4 * 4];
            const float4 c4 = *(const float4*)&Cp[(size_t)t * DSTATE + j4 * 4];
            hs[j4 * 4 + 0] = fmaf(dA, hs[j4 * 4 + 0], dtx * b4.x);
            hs[j4 * 4 + 1] = fmaf(dA, hs[j4 * 4 + 1], dtx * b4.y);
            hs[j4 * 4 + 2] = fmaf(dA, hs[j4 * 4 + 2], dtx * b4.z);
            hs[j4 * 4 + 3] = fmaf(dA, hs[j4 * 4 + 3], dtx * b4.w);
            y = fmaf(hs[j4 * 4 + 0], c4.x, y);
            y = fmaf(hs[j4 * 4 + 1], c4.y, y);
            y = fmaf(hs[j4 * 4 + 2], c4.z, y);
            y = fmaf(hs[j4 * 4 + 3], c4.w, y);
        }
        yo[(size_t)t * DINNER] = y;
    }
}

// ---------------------------------------------------------------------------
// Gate + RMSNorm. Writes into zx cols [1024,2048) for the output GEMM.
// ---------------------------------------------------------------------------
__global__ __launch_bounds__(256)
void gate_kernel(const float* __restrict__ yb,
                 float* __restrict__ zx,
                 const float* __restrict__ nw)
{
    const int row = blockIdx.x;
    const int c4 = threadIdx.x * 4;

    const float4 y = *(const float4*)&yb[(size_t)row * DINNER + c4];
    const float4 z = *(const float4*)&zx[(size_t)row * DINPROJ + c4];
    float4 g;
    g.x = y.x * silu_f(z.x);
    g.y = y.y * silu_f(z.y);
    g.z = y.z * silu_f(z.z);
    g.w = y.w * silu_f(z.w);

    float local = g.x * g.x + g.y * g.y + g.z * g.z + g.w * g.w;
#pragma unroll
    for (int m = 32; m >= 1; m >>= 1) local += __shfl_xor(local, m, 64);

    __shared__ float red[4];
    if ((threadIdx.x & 63) == 0) red[threadIdx.x >> 6] = local;
    __syncthreads();
    const float total = red[0] + red[1] + red[2] + red[3];
    const float scale = rsqrtf(total * (1.0f / (float)DINNER) + 1e-5f);

    const float4 w = *(const float4*)&nw[c4];
    float4 o;
    o.x = g.x * scale * w.x;
    o.y = g.y * scale * w.y;
    o.z = g.z * scale * w.z;
    o.w = g.w * scale * w.w;
    *(float4*)&zx[(size_t)row * DINPROJ + DINNER + c4] = o;
}

// ---------------------------------------------------------------------------
extern "C" void kernel_launch(void* const* d_in, const int* in_sizes, int n_in,
                              void* d_out, int out_size, void* d_ws, size_t ws_size,
                              hipStream_t stream)
{
    const float* x_in    = (const float*)d_in[0];
    const float* in_w    = (const float*)d_in[1];
    const float* conv_w  = (const float*)d_in[2];
    const float* conv_b  = (const float*)d_in[3];
    const float* dt_bias = (const float*)d_in[4];
    const float* A_log   = (const float*)d_in[5];
    const float* D_skip  = (const float*)d_in[6];
    const float* norm_w  = (const float*)d_in[7];
    const float* out_w   = (const float*)d_in[8];
    float* out = (float*)d_out;

    float* ws   = (float*)d_ws;
    float* zx   = ws;                               // 8192*2320 = 19,005,440
    float* xh   = zx   + (size_t)ROWS * DINPROJ;    // 8,388,608
    float* Bb   = xh   + (size_t)ROWS * DINNER;     // 1,048,576
    float* Cb   = Bb   + (size_t)ROWS * DSTATE;     // 1,048,576
    float* dtb  = Cb   + (size_t)ROWS * DSTATE;     // 131,072
    float* dAb  = dtb  + (size_t)ROWS * NHEADS;     // 131,072
    float* yb   = dAb  + (size_t)ROWS * NHEADS;     // 8,388,608
    float* hloc = yb   + (size_t)ROWS * DINNER;     // 64*32*8192 = 16,777,216
    float* ptot = hloc + (size_t)BATCH * NHEADS * NSEG * DSTATE * HEADDIM; // 2048
    // total ~54.9M floats = ~220 MB

    for (int layer = 0; layer < 2; ++layer) {
        const float* xl = (layer == 0) ? x_in : out;

        gemm_f32<<<dim3((DINPROJ + 127) / 128, ROWS / 128), 256, 0, stream>>>(
            xl, DMODEL,
            in_w + (size_t)layer * DMODEL * DINPROJ, DINPROJ,
            zx, DINPROJ,
            DINPROJ, DMODEL);

        conv_kernel<<<ROWS, CONVDIM / 4, 0, stream>>>(
            zx,
            conv_w + (size_t)layer * DCONV * CONVDIM,
            conv_b + (size_t)layer * CONVDIM,
            dt_bias + (size_t)layer * NHEADS,
            A_log + (size_t)layer * NHEADS,
            xh, Bb, Cb, dtb, dAb);

        scan_local<<<BATCH * NHEADS * NSEG, 64, 0, stream>>>(
            xh, Bb, dtb, dAb, hloc, ptot);

        combine_kernel<<<BATCH * NHEADS * 8, 256, 0, stream>>>(hloc, ptot);

        scan_full<<<BATCH * NHEADS * NSEG, 64, 0, stream>>>(
            xh, Bb, Cb, dtb, dAb, hloc,
            D_skip + (size_t)layer * NHEADS, yb);

        gate_kernel<<<ROWS, 256, 0, stream>>>(
            yb, zx, norm_w + (size_t)layer * DINNER);

        gemm_f32<<<dim3(DMODEL / 128, ROWS / 128), 256, 0, stream>>>(
            zx + DINNER, DINPROJ,
            out_w + (size_t)layer * DINNER * DMODEL, DMODEL,
            out, DMODEL,
            DMODEL, DINNER);
    }
}

// Round 4
// 960.708 us; speedup vs baseline: 4.6234x; 1.5089x over previous
//
#include <hip/hip_runtime.h>
#include <hip/hip_bf16.h>
#include <cstddef>
#include <cstdint>

// Mamba2 (2 layers). GEMMs via split-bf16 MFMA (C = AhBh + AhBl + AlBh),
// segmented-parallel selective scan (NSEG=32), fused gate->bf16-split.
//
// Workspace (floats): zx 19.0M | xh 8.39M | Bb 1.05M | Cb 1.05M | dtb .13M |
// dAb .13M | yb 8.39M | UNION 16.78M {Ah/Al | hloc | yh/yl} | Bt 1.25M |
// Wt 0.52M | ptot 2k  => 226.8 MB (budget: 253 MB proven safe).

#define BATCH 4
#define SEQ   2048
#define DMODEL 512
#define DINNER 1024
#define DSTATE 128
#define HEADDIM 64
#define NHEADS 16
#define DCONV 4
#define CONVDIM 1280
#define DINPROJ 2320
#define NPAD_IN 2432          // 19 * 128
#define ROWS (BATCH * SEQ)    // 8192
#define NSEG 32
#define TSEG 64               // SEQ / NSEG

typedef __attribute__((ext_vector_type(8))) short bf16x8;
typedef __attribute__((ext_vector_type(4))) float f32x4;

__device__ __forceinline__ float silu_f(float x) {
    return x * (1.0f / (1.0f + __expf(-x)));
}
__device__ __forceinline__ unsigned short f2bfu(float f) {  // RNE fp32->bf16
    unsigned u = __float_as_uint(f);
    unsigned r = u + 0x7FFFu + ((u >> 16) & 1u);
    return (unsigned short)(r >> 16);
}
__device__ __forceinline__ float bfu2f(unsigned short h) {
    return __uint_as_float(((unsigned)h) << 16);
}

// ---------------------------------------------------------------------------
// Split fp32 A[M*K] -> Ah, Al (bf16). 8 elems/thread.
// ---------------------------------------------------------------------------
__global__ __launch_bounds__(256)
void split_a_kernel(const float* __restrict__ A,
                    unsigned short* __restrict__ Ah,
                    unsigned short* __restrict__ Al)
{
    const size_t i = ((size_t)blockIdx.x * 256 + threadIdx.x) * 8;
    const float4 a = *(const float4*)&A[i];
    const float4 b = *(const float4*)&A[i + 4];
    float v[8] = {a.x, a.y, a.z, a.w, b.x, b.y, b.z, b.w};
    unsigned hv[8], lv[8];
#pragma unroll
    for (int j = 0; j < 8; ++j) {
        hv[j] = f2bfu(v[j]);
        lv[j] = f2bfu(v[j] - bfu2f((unsigned short)hv[j]));
    }
    uint4 ph = make_uint4(hv[0] | (hv[1] << 16), hv[2] | (hv[3] << 16),
                          hv[4] | (hv[5] << 16), hv[6] | (hv[7] << 16));
    uint4 pl = make_uint4(lv[0] | (lv[1] << 16), lv[2] | (lv[3] << 16),
                          lv[4] | (lv[5] << 16), lv[6] | (lv[7] << 16));
    *(uint4*)&Ah[i] = ph;
    *(uint4*)&Al[i] = pl;
}

// ---------------------------------------------------------------------------
// Transpose + split weight W[K][N] fp32 -> Oh/Ol[Npad][K] bf16 (n >= N -> 0).
// grid = (Npad/32, K/32), 256 threads, LDS 32x33 tile.
// ---------------------------------------------------------------------------
__global__ __launch_bounds__(256)
void tsplit_w_kernel(const float* __restrict__ W, int K, int N,
                     unsigned short* __restrict__ Oh,
                     unsigned short* __restrict__ Ol)
{
    __shared__ float tile[32][33];
    const int n0 = blockIdx.x * 32, k0 = blockIdx.y * 32;
    const int c = threadIdx.x & 31, r8 = threadIdx.x >> 5;
    const int n = n0 + c;
#pragma unroll
    for (int i = 0; i < 4; ++i) {
        const int k = r8 + i * 8;
        float v = 0.0f;
        if (n < N) v = W[(size_t)(k0 + k) * N + n];
        tile[c][k] = v;
    }
    __syncthreads();
#pragma unroll
    for (int i = 0; i < 4; ++i) {
        const int nl = r8 + i * 8;
        const float v = tile[nl][c];
        const unsigned short h = f2bfu(v);
        const unsigned short l = f2bfu(v - bfu2f(h));
        const size_t o = (size_t)(n0 + nl) * K + k0 + c;
        Oh[o] = h;
        Ol[o] = l;
    }
}

// ---------------------------------------------------------------------------
// Split-bf16 MFMA GEMM: C[M][N](fp32,ldc) = A @ B with
// A given as Ah/Al [M][K] bf16 (k-contig), B as Bh/Bl [Npad][K] bf16
// (pre-transposed, k-contig). 128x128 tile, BK=32, 4 waves (2x2 of 64x64),
// mfma_f32_16x16x32_bf16, 3 passes (hh, hl, lh).
// ---------------------------------------------------------------------------
__global__ __launch_bounds__(256)
void gemm_bf16s(const unsigned short* __restrict__ Ah,
                const unsigned short* __restrict__ Al,
                const unsigned short* __restrict__ Bh,
                const unsigned short* __restrict__ Bl,
                float* __restrict__ C, int ldc, int N, int K)
{
    __shared__ __align__(16) unsigned short As[2][128 * 32];
    __shared__ __align__(16) unsigned short Bs[2][128 * 32];

    const int tid = threadIdx.x;
    const int w = tid >> 6, lane = tid & 63;
    const int wm = w >> 1, wn = w & 1;
    const int row0 = blockIdx.y * 128, col0 = blockIdx.x * 128;

    const int srow = tid >> 1;       // staging row 0..127
    const int sk   = (tid & 1) * 16; // staging k-offset (16 elems = 32B)

    const int lr = lane & 15;        // row/col within a 16-tile
    const int lk = (lane >> 4) * 8;  // k-offset of the fragment

    f32x4 acc[4][4];
#pragma unroll
    for (int i = 0; i < 4; ++i)
#pragma unroll
        for (int j = 0; j < 4; ++j) acc[i][j] = (f32x4){0.f, 0.f, 0.f, 0.f};

    for (int k0 = 0; k0 < K; k0 += 32) {
        const size_t ga = (size_t)(row0 + srow) * K + k0 + sk;
        const size_t gb = (size_t)(col0 + srow) * K + k0 + sk;
        const uint4 vah0 = *(const uint4*)&Ah[ga];
        const uint4 vah1 = *(const uint4*)&Ah[ga + 8];
        const uint4 val0 = *(const uint4*)&Al[ga];
        const uint4 val1 = *(const uint4*)&Al[ga + 8];
        const uint4 vbh0 = *(const uint4*)&Bh[gb];
        const uint4 vbh1 = *(const uint4*)&Bh[gb + 8];
        const uint4 vbl0 = *(const uint4*)&Bl[gb];
        const uint4 vbl1 = *(const uint4*)&Bl[gb + 8];
        __syncthreads();             // previous iter's readers done
        const int so = srow * 32 + sk;
        *(uint4*)&As[0][so] = vah0;  *(uint4*)&As[0][so + 8] = vah1;
        *(uint4*)&As[1][so] = val0;  *(uint4*)&As[1][so + 8] = val1;
        *(uint4*)&Bs[0][so] = vbh0;  *(uint4*)&Bs[0][so + 8] = vbh1;
        *(uint4*)&Bs[1][so] = vbl0;  *(uint4*)&Bs[1][so + 8] = vbl1;
        __syncthreads();

        bf16x8 a_h[4], a_l[4], b_h[4], b_l[4];
#pragma unroll
        for (int mt = 0; mt < 4; ++mt) {
            const int r = wm * 64 + mt * 16 + lr;
            a_h[mt] = *(const bf16x8*)&As[0][r * 32 + lk];
            a_l[mt] = *(const bf16x8*)&As[1][r * 32 + lk];
        }
#pragma unroll
        for (int nt = 0; nt < 4; ++nt) {
            const int c = wn * 64 + nt * 16 + lr;
            b_h[nt] = *(const bf16x8*)&Bs[0][c * 32 + lk];
            b_l[nt] = *(const bf16x8*)&Bs[1][c * 32 + lk];
        }
#pragma unroll
        for (int mt = 0; mt < 4; ++mt)
#pragma unroll
            for (int nt = 0; nt < 4; ++nt) {
                acc[mt][nt] = __builtin_amdgcn_mfma_f32_16x16x32_bf16(a_h[mt], b_h[nt], acc[mt][nt], 0, 0, 0);
                acc[mt][nt] = __builtin_amdgcn_mfma_f32_16x16x32_bf16(a_h[mt], b_l[nt], acc[mt][nt], 0, 0, 0);
                acc[mt][nt] = __builtin_amdgcn_mfma_f32_16x16x32_bf16(a_l[mt], b_h[nt], acc[mt][nt], 0, 0, 0);
            }
    }

    const int crow = (lane >> 4) * 4;  // C/D: col = lane&15, row = (lane>>4)*4+r
#pragma unroll
    for (int mt = 0; mt < 4; ++mt)
#pragma unroll
        for (int nt = 0; nt < 4; ++nt) {
            const int cc = col0 + wn * 64 + nt * 16 + lr;
            if (cc < N) {
#pragma unroll
                for (int r = 0; r < 4; ++r)
                    C[(size_t)(row0 + wm * 64 + mt * 16 + crow + r) * ldc + cc] = acc[mt][nt][r];
            }
        }
}

// ---------------------------------------------------------------------------
// Depthwise causal conv (4 taps) + bias + SiLU + dt/dA precompute.
// ---------------------------------------------------------------------------
__global__ __launch_bounds__(320)
void conv_kernel(const float* __restrict__ zx,
                 const float* __restrict__ cw,
                 const float* __restrict__ cb,
                 const float* __restrict__ dtbias,
                 const float* __restrict__ alog,
                 float* __restrict__ xh,
                 float* __restrict__ Bb,
                 float* __restrict__ Cb,
                 float* __restrict__ dtb,
                 float* __restrict__ dAb)
{
    const int row = blockIdx.x;
    const int l   = row & (SEQ - 1);
    const int c4  = threadIdx.x * 4;

    float4 acc = *(const float4*)&cb[c4];
#pragma unroll
    for (int k = 0; k < DCONV; ++k) {
        const int lk = l - (DCONV - 1) + k;
        if (lk >= 0) {
            const float4 v = *(const float4*)&zx[(size_t)(row - (DCONV - 1) + k) * DINPROJ + DINNER + c4];
            const float4 w = *(const float4*)&cw[k * CONVDIM + c4];
            acc.x = fmaf(v.x, w.x, acc.x);
            acc.y = fmaf(v.y, w.y, acc.y);
            acc.z = fmaf(v.z, w.z, acc.z);
            acc.w = fmaf(v.w, w.w, acc.w);
        }
    }
    acc.x = silu_f(acc.x);
    acc.y = silu_f(acc.y);
    acc.z = silu_f(acc.z);
    acc.w = silu_f(acc.w);

    if (c4 < DINNER) {
        *(float4*)&xh[(size_t)row * DINNER + c4] = acc;
    } else if (c4 < DINNER + DSTATE) {
        *(float4*)&Bb[(size_t)row * DSTATE + (c4 - DINNER)] = acc;
    } else {
        *(float4*)&Cb[(size_t)row * DSTATE + (c4 - DINNER - DSTATE)] = acc;
    }

    if (threadIdx.x < NHEADS) {
        const int hh = threadIdx.x;
        const float raw = zx[(size_t)row * DINPROJ + (DINNER + CONVDIM) + hh] + dtbias[hh];
        const float dtv = (raw > 20.0f) ? raw : log1pf(expf(raw));
        const float a = expf(alog[hh]);
        dtb[row * NHEADS + hh] = dtv;
        dAb[row * NHEADS + hh] = expf(-a * dtv);
    }
}

// ---------------------------------------------------------------------------
// Pass 1: local scan per segment, h0 = 0, state-only.
// ---------------------------------------------------------------------------
__global__ __launch_bounds__(64, 2)
void scan_local(const float* __restrict__ xh,
                const float* __restrict__ Bb,
                const float* __restrict__ dtb,
                const float* __restrict__ dAb,
                float* __restrict__ hloc,
                float* __restrict__ ptot)
{
    const int bid = blockIdx.x;
    const int seg = bid & (NSEG - 1);
    const int h   = (bid >> 5) & (NHEADS - 1);
    const int b   = bid >> 9;
    const int lane = threadIdx.x;

    float hs[DSTATE];
#pragma unroll
    for (int j = 0; j < DSTATE; ++j) hs[j] = 0.0f;
    float prun = 1.0f;

    const size_t row0 = (size_t)b * SEQ + (size_t)seg * TSEG;
    const float* __restrict__ Bp  = Bb  + row0 * DSTATE;
    const float* __restrict__ xp  = xh  + row0 * DINNER + h * HEADDIM + lane;
    const float* __restrict__ dAp = dAb + row0 * NHEADS + h;
    const float* __restrict__ dtp = dtb + row0 * NHEADS + h;

    for (int t = 0; t < TSEG; ++t) {
        const float dA  = dAp[t * NHEADS];
        const float dtx = dtp[t * NHEADS] * xp[(size_t)t * DINNER];
        prun *= dA;
#pragma unroll
        for (int j4 = 0; j4 < DSTATE / 4; ++j4) {
            const float4 b4 = *(const float4*)&Bp[(size_t)t * DSTATE + j4 * 4];
            hs[j4 * 4 + 0] = fmaf(dA, hs[j4 * 4 + 0], dtx * b4.x);
            hs[j4 * 4 + 1] = fmaf(dA, hs[j4 * 4 + 1], dtx * b4.y);
            hs[j4 * 4 + 2] = fmaf(dA, hs[j4 * 4 + 2], dtx * b4.z);
            hs[j4 * 4 + 3] = fmaf(dA, hs[j4 * 4 + 3], dtx * b4.w);
        }
    }

    const size_t sidx = (size_t)((b * NHEADS + h) * NSEG + seg) * (DSTATE * HEADDIM);
#pragma unroll
    for (int j = 0; j < DSTATE; ++j)
        hloc[sidx + (size_t)j * HEADDIM + lane] = hs[j];
    if (lane == 0)
        ptot[(b * NHEADS + h) * NSEG + seg] = prun;
}

// ---------------------------------------------------------------------------
// Pass 2: sequential combine over 32 segments (in-place: hloc becomes h0).
// ---------------------------------------------------------------------------
__global__ __launch_bounds__(256)
void combine_kernel(float* __restrict__ hloc,
                    const float* __restrict__ ptot)
{
    const int bid = blockIdx.x;
    const int bh = bid >> 3;
    const int chunk = bid & 7;
    const int e0 = chunk * 1024 + threadIdx.x * 4;

    float4 s = make_float4(0.f, 0.f, 0.f, 0.f);
    for (int k = 0; k < NSEG; ++k) {
        float* p = &hloc[((size_t)bh * NSEG + k) * (DSTATE * HEADDIM) + e0];
        const float4 v = *(const float4*)p;
        *(float4*)p = s;
        const float pt = ptot[bh * NSEG + k];
        s.x = fmaf(pt, s.x, v.x);
        s.y = fmaf(pt, s.y, v.y);
        s.z = fmaf(pt, s.z, v.z);
        s.w = fmaf(pt, s.w, v.w);
    }
}

// ---------------------------------------------------------------------------
// Pass 3: full scan per segment with true h0; writes y directly (fp32).
// ---------------------------------------------------------------------------
__global__ __launch_bounds__(64, 2)
void scan_full(const float* __restrict__ xh,
               const float* __restrict__ Bb,
               const float* __restrict__ Cb,
               const float* __restrict__ dtb,
               const float* __restrict__ dAb,
               const float* __restrict__ h0,
               const float* __restrict__ dskip,
               float* __restrict__ yb)
{
    const int bid = blockIdx.x;
    const int seg = bid & (NSEG - 1);
    const int h   = (bid >> 5) & (NHEADS - 1);
    const int b   = bid >> 9;
    const int lane = threadIdx.x;

    const size_t sidx = (size_t)((b * NHEADS + h) * NSEG + seg) * (DSTATE * HEADDIM);
    float hs[DSTATE];
#pragma unroll
    for (int j = 0; j < DSTATE; ++j)
        hs[j] = h0[sidx + (size_t)j * HEADDIM + lane];

    const float dsk = dskip[h];
    const size_t row0 = (size_t)b * SEQ + (size_t)seg * TSEG;
    const float* __restrict__ Bp  = Bb  + row0 * DSTATE;
    const float* __restrict__ Cp  = Cb  + row0 * DSTATE;
    const float* __restrict__ xp  = xh  + row0 * DINNER + h * HEADDIM + lane;
    const float* __restrict__ dAp = dAb + row0 * NHEADS + h;
    const float* __restrict__ dtp = dtb + row0 * NHEADS + h;
    float* __restrict__ yo = yb + row0 * DINNER + h * HEADDIM + lane;

    for (int t = 0; t < TSEG; ++t) {
        const float dA  = dAp[t * NHEADS];
        const float xv  = xp[(size_t)t * DINNER];
        const float dtx = dtp[t * NHEADS] * xv;
        float y = dsk * xv;
#pragma unroll
        for (int j4 = 0; j4 < DSTATE / 4; ++j4) {
            const float4 b4 = *(const float4*)&Bp[(size_t)t * DSTATE + j4 * 4];
            const float4 c4 = *(const float4*)&Cp[(size_t)t * DSTATE + j4 * 4];
            hs[j4 * 4 + 0] = fmaf(dA, hs[j4 * 4 + 0], dtx * b4.x);
            hs[j4 * 4 + 1] = fmaf(dA, hs[j4 * 4 + 1], dtx * b4.y);
            hs[j4 * 4 + 2] = fmaf(dA, hs[j4 * 4 + 2], dtx * b4.z);
            hs[j4 * 4 + 3] = fmaf(dA, hs[j4 * 4 + 3], dtx * b4.w);
            y = fmaf(hs[j4 * 4 + 0], c4.x, y);
            y = fmaf(hs[j4 * 4 + 1], c4.y, y);
            y = fmaf(hs[j4 * 4 + 2], c4.z, y);
            y = fmaf(hs[j4 * 4 + 3], c4.w, y);
        }
        yo[(size_t)t * DINNER] = y;
    }
}

// ---------------------------------------------------------------------------
// Gate + RMSNorm; writes ynorm as split-bf16 planes (A operand of out-proj).
// ---------------------------------------------------------------------------
__global__ __launch_bounds__(256)
void gate_kernel(const float* __restrict__ yb,
                 const float* __restrict__ zx,
                 const float* __restrict__ nw,
                 unsigned short* __restrict__ yh,
                 unsigned short* __restrict__ yl)
{
    const int row = blockIdx.x;
    const int c4 = threadIdx.x * 4;

    const float4 y = *(const float4*)&yb[(size_t)row * DINNER + c4];
    const float4 z = *(const float4*)&zx[(size_t)row * DINPROJ + c4];
    float4 g;
    g.x = y.x * silu_f(z.x);
    g.y = y.y * silu_f(z.y);
    g.z = y.z * silu_f(z.z);
    g.w = y.w * silu_f(z.w);

    float local = g.x * g.x + g.y * g.y + g.z * g.z + g.w * g.w;
#pragma unroll
    for (int m = 32; m >= 1; m >>= 1) local += __shfl_xor(local, m, 64);

    __shared__ float red[4];
    if ((threadIdx.x & 63) == 0) red[threadIdx.x >> 6] = local;
    __syncthreads();
    const float total = red[0] + red[1] + red[2] + red[3];
    const float scale = rsqrtf(total * (1.0f / (float)DINNER) + 1e-5f);

    const float4 w = *(const float4*)&nw[c4];
    float o[4];
    o[0] = g.x * scale * w.x;
    o[1] = g.y * scale * w.y;
    o[2] = g.z * scale * w.z;
    o[3] = g.w * scale * w.w;

    unsigned hv[4], lv[4];
#pragma unroll
    for (int j = 0; j < 4; ++j) {
        hv[j] = f2bfu(o[j]);
        lv[j] = f2bfu(o[j] - bfu2f((unsigned short)hv[j]));
    }
    const size_t oi = (size_t)row * DINNER + c4;
    *(uint2*)&yh[oi] = make_uint2(hv[0] | (hv[1] << 16), hv[2] | (hv[3] << 16));
    *(uint2*)&yl[oi] = make_uint2(lv[0] | (lv[1] << 16), lv[2] | (lv[3] << 16));
}

// ---------------------------------------------------------------------------
extern "C" void kernel_launch(void* const* d_in, const int* in_sizes, int n_in,
                              void* d_out, int out_size, void* d_ws, size_t ws_size,
                              hipStream_t stream)
{
    const float* x_in    = (const float*)d_in[0];
    const float* in_w    = (const float*)d_in[1];
    const float* conv_w  = (const float*)d_in[2];
    const float* conv_b  = (const float*)d_in[3];
    const float* dt_bias = (const float*)d_in[4];
    const float* A_log   = (const float*)d_in[5];
    const float* D_skip  = (const float*)d_in[6];
    const float* norm_w  = (const float*)d_in[7];
    const float* out_w   = (const float*)d_in[8];
    float* out = (float*)d_out;

    float* ws   = (float*)d_ws;
    float* zx   = ws;                               // 19,005,440 f
    float* xh   = zx   + (size_t)ROWS * DINPROJ;    //  8,388,608 f
    float* Bb   = xh   + (size_t)ROWS * DINNER;     //  1,048,576 f
    float* Cb   = Bb   + (size_t)ROWS * DSTATE;     //  1,048,576 f
    float* dtb  = Cb   + (size_t)ROWS * DSTATE;     //    131,072 f
    float* dAb  = dtb  + (size_t)ROWS * NHEADS;     //    131,072 f
    float* yb   = dAb  + (size_t)ROWS * NHEADS;     //  8,388,608 f
    float* UN   = yb   + (size_t)ROWS * DINNER;     // 16,777,216 f (union)
    float* BtF  = UN   + (size_t)16777216;          //  1,245,184 f
    float* WtF  = BtF  + (size_t)1245184;           //    524,288 f
    float* ptot = WtF  + (size_t)524288;            //      2,048 f

    // union region overlays (disjoint lifetimes, stream-ordered):
    unsigned short* Ah = (unsigned short*)UN;                 // [8192][512]
    unsigned short* Al = Ah + (size_t)ROWS * DMODEL;
    float*          hloc = UN;                                // 16.78M f
    unsigned short* yh = (unsigned short*)UN;                 // [8192][1024]
    unsigned short* yl = yh + (size_t)ROWS * DINNER;

    unsigned short* Bth = (unsigned short*)BtF;               // [2432][512]
    unsigned short* Btl = Bth + (size_t)NPAD_IN * DMODEL;
    unsigned short* Wth = (unsigned short*)WtF;               // [512][1024]
    unsigned short* Wtl = Wth + (size_t)DMODEL * DINNER;

    for (int layer = 0; layer < 2; ++layer) {
        const float* xl = (layer == 0) ? x_in : out;

        // A split: x (8192x512) -> Ah/Al
        split_a_kernel<<<(ROWS * DMODEL) / (256 * 8), 256, 0, stream>>>(xl, Ah, Al);

        // in_w (512x2320) -> Bth/Btl [2432][512]
        tsplit_w_kernel<<<dim3(NPAD_IN / 32, DMODEL / 32), 256, 0, stream>>>(
            in_w + (size_t)layer * DMODEL * DINPROJ, DMODEL, DINPROJ, Bth, Btl);

        // zx = x @ in_w  (M=8192, N=2320 (pad 2432), K=512)
        gemm_bf16s<<<dim3(NPAD_IN / 128, ROWS / 128), 256, 0, stream>>>(
            Ah, Al, Bth, Btl, zx, DINPROJ, DINPROJ, DMODEL);

        conv_kernel<<<ROWS, CONVDIM / 4, 0, stream>>>(
            zx,
            conv_w + (size_t)layer * DCONV * CONVDIM,
            conv_b + (size_t)layer * CONVDIM,
            dt_bias + (size_t)layer * NHEADS,
            A_log + (size_t)layer * NHEADS,
            xh, Bb, Cb, dtb, dAb);

        scan_local<<<BATCH * NHEADS * NSEG, 64, 0, stream>>>(
            xh, Bb, dtb, dAb, hloc, ptot);

        combine_kernel<<<BATCH * NHEADS * 8, 256, 0, stream>>>(hloc, ptot);

        scan_full<<<BATCH * NHEADS * NSEG, 64, 0, stream>>>(
            xh, Bb, Cb, dtb, dAb, hloc,
            D_skip + (size_t)layer * NHEADS, yb);

        gate_kernel<<<ROWS, 256, 0, stream>>>(
            yb, zx, norm_w + (size_t)layer * DINNER, yh, yl);

        // out_w (1024x512) -> Wth/Wtl [512][1024]
        tsplit_w_kernel<<<dim3(DMODEL / 32, DINNER / 32), 256, 0, stream>>>(
            out_w + (size_t)layer * DINNER * DMODEL, DINNER, DMODEL, Wth, Wtl);

        // out = ynorm @ out_w  (M=8192, N=512, K=1024)
        gemm_bf16s<<<dim3(DMODEL / 128, ROWS / 128), 256, 0, stream>>>(
            yh, yl, Wth, Wtl, out, DMODEL, DMODEL, DINNER);
    }
}

// Round 5
// 955.977 us; speedup vs baseline: 4.6462x; 1.0049x over previous
//
#include <hip/hip_runtime.h>
#include <hip/hip_bf16.h>
#include <cstddef>
#include <cstdint>

// Mamba2 (2 layers). GEMMs via split-bf16 MFMA (C = AhBh + AhBl + AlBh),
// segmented-parallel selective scan (NSEG=32), scan blocks split the state
// dim in half (hs[64]/lane, LDS-staged operands, atomicAdd y-merge).
//
// Workspace (floats): zx 19.0M | xh 8.39M | Bb 1.05M | Cb 1.05M | dtb .13M |
// dAb .13M | yb 8.39M | UNION 16.78M {Ah/Al | hloc | yh/yl} | Bt 1.25M |
// Wt 0.52M | ptot 2k  => 226.8 MB (budget: 253 MB proven safe).

#define BATCH 4
#define SEQ   2048
#define DMODEL 512
#define DINNER 1024
#define DSTATE 128
#define HEADDIM 64
#define NHEADS 16
#define DCONV 4
#define CONVDIM 1280
#define DINPROJ 2320
#define NPAD_IN 2432          // 19 * 128
#define ROWS (BATCH * SEQ)    // 8192
#define NSEG 32
#define TSEG 64               // SEQ / NSEG
#define CH 8                  // steps staged per LDS chunk
#define NCH (TSEG / CH)       // 8 chunks per segment

typedef __attribute__((ext_vector_type(8))) short bf16x8;
typedef __attribute__((ext_vector_type(4))) float f32x4;

__device__ __forceinline__ float silu_f(float x) {
    return x * (1.0f / (1.0f + __expf(-x)));
}
__device__ __forceinline__ unsigned short f2bfu(float f) {  // RNE fp32->bf16
    unsigned u = __float_as_uint(f);
    unsigned r = u + 0x7FFFu + ((u >> 16) & 1u);
    return (unsigned short)(r >> 16);
}
__device__ __forceinline__ float bfu2f(unsigned short h) {
    return __uint_as_float(((unsigned)h) << 16);
}

// ---------------------------------------------------------------------------
// Zero-fill (for the atomic y buffer).
// ---------------------------------------------------------------------------
__global__ __launch_bounds__(256)
void zero_kernel(float* __restrict__ p)
{
    const size_t i = ((size_t)blockIdx.x * 256 + threadIdx.x) * 16;
#pragma unroll
    for (int j = 0; j < 4; ++j)
        *(float4*)&p[i + j * 4] = make_float4(0.f, 0.f, 0.f, 0.f);
}

// ---------------------------------------------------------------------------
// Split fp32 A[M*K] -> Ah, Al (bf16). 8 elems/thread.
// ---------------------------------------------------------------------------
__global__ __launch_bounds__(256)
void split_a_kernel(const float* __restrict__ A,
                    unsigned short* __restrict__ Ah,
                    unsigned short* __restrict__ Al)
{
    const size_t i = ((size_t)blockIdx.x * 256 + threadIdx.x) * 8;
    const float4 a = *(const float4*)&A[i];
    const float4 b = *(const float4*)&A[i + 4];
    float v[8] = {a.x, a.y, a.z, a.w, b.x, b.y, b.z, b.w};
    unsigned hv[8], lv[8];
#pragma unroll
    for (int j = 0; j < 8; ++j) {
        hv[j] = f2bfu(v[j]);
        lv[j] = f2bfu(v[j] - bfu2f((unsigned short)hv[j]));
    }
    uint4 ph = make_uint4(hv[0] | (hv[1] << 16), hv[2] | (hv[3] << 16),
                          hv[4] | (hv[5] << 16), hv[6] | (hv[7] << 16));
    uint4 pl = make_uint4(lv[0] | (lv[1] << 16), lv[2] | (lv[3] << 16),
                          lv[4] | (lv[5] << 16), lv[6] | (lv[7] << 16));
    *(uint4*)&Ah[i] = ph;
    *(uint4*)&Al[i] = pl;
}

// ---------------------------------------------------------------------------
// Transpose + split weight W[K][N] fp32 -> Oh/Ol[Npad][K] bf16 (n >= N -> 0).
// ---------------------------------------------------------------------------
__global__ __launch_bounds__(256)
void tsplit_w_kernel(const float* __restrict__ W, int K, int N,
                     unsigned short* __restrict__ Oh,
                     unsigned short* __restrict__ Ol)
{
    __shared__ float tile[32][33];
    const int n0 = blockIdx.x * 32, k0 = blockIdx.y * 32;
    const int c = threadIdx.x & 31, r8 = threadIdx.x >> 5;
    const int n = n0 + c;
#pragma unroll
    for (int i = 0; i < 4; ++i) {
        const int k = r8 + i * 8;
        float v = 0.0f;
        if (n < N) v = W[(size_t)(k0 + k) * N + n];
        tile[c][k] = v;
    }
    __syncthreads();
#pragma unroll
    for (int i = 0; i < 4; ++i) {
        const int nl = r8 + i * 8;
        const float v = tile[nl][c];
        const unsigned short h = f2bfu(v);
        const unsigned short l = f2bfu(v - bfu2f(h));
        const size_t o = (size_t)(n0 + nl) * K + k0 + c;
        Oh[o] = h;
        Ol[o] = l;
    }
}

// ---------------------------------------------------------------------------
// Split-bf16 MFMA GEMM (unchanged from passing round 4).
// ---------------------------------------------------------------------------
__global__ __launch_bounds__(256)
void gemm_bf16s(const unsigned short* __restrict__ Ah,
                const unsigned short* __restrict__ Al,
                const unsigned short* __restrict__ Bh,
                const unsigned short* __restrict__ Bl,
                float* __restrict__ C, int ldc, int N, int K)
{
    __shared__ __align__(16) unsigned short As[2][128 * 32];
    __shared__ __align__(16) unsigned short Bs[2][128 * 32];

    const int tid = threadIdx.x;
    const int w = tid >> 6, lane = tid & 63;
    const int wm = w >> 1, wn = w & 1;
    const int row0 = blockIdx.y * 128, col0 = blockIdx.x * 128;

    const int srow = tid >> 1;
    const int sk   = (tid & 1) * 16;

    const int lr = lane & 15;
    const int lk = (lane >> 4) * 8;

    f32x4 acc[4][4];
#pragma unroll
    for (int i = 0; i < 4; ++i)
#pragma unroll
        for (int j = 0; j < 4; ++j) acc[i][j] = (f32x4){0.f, 0.f, 0.f, 0.f};

    for (int k0 = 0; k0 < K; k0 += 32) {
        const size_t ga = (size_t)(row0 + srow) * K + k0 + sk;
        const size_t gb = (size_t)(col0 + srow) * K + k0 + sk;
        const uint4 vah0 = *(const uint4*)&Ah[ga];
        const uint4 vah1 = *(const uint4*)&Ah[ga + 8];
        const uint4 val0 = *(const uint4*)&Al[ga];
        const uint4 val1 = *(const uint4*)&Al[ga + 8];
        const uint4 vbh0 = *(const uint4*)&Bh[gb];
        const uint4 vbh1 = *(const uint4*)&Bh[gb + 8];
        const uint4 vbl0 = *(const uint4*)&Bl[gb];
        const uint4 vbl1 = *(const uint4*)&Bl[gb + 8];
        __syncthreads();
        const int so = srow * 32 + sk;
        *(uint4*)&As[0][so] = vah0;  *(uint4*)&As[0][so + 8] = vah1;
        *(uint4*)&As[1][so] = val0;  *(uint4*)&As[1][so + 8] = val1;
        *(uint4*)&Bs[0][so] = vbh0;  *(uint4*)&Bs[0][so + 8] = vbh1;
        *(uint4*)&Bs[1][so] = vbl0;  *(uint4*)&Bs[1][so + 8] = vbl1;
        __syncthreads();

        bf16x8 a_h[4], a_l[4], b_h[4], b_l[4];
#pragma unroll
        for (int mt = 0; mt < 4; ++mt) {
            const int r = wm * 64 + mt * 16 + lr;
            a_h[mt] = *(const bf16x8*)&As[0][r * 32 + lk];
            a_l[mt] = *(const bf16x8*)&As[1][r * 32 + lk];
        }
#pragma unroll
        for (int nt = 0; nt < 4; ++nt) {
            const int c = wn * 64 + nt * 16 + lr;
            b_h[nt] = *(const bf16x8*)&Bs[0][c * 32 + lk];
            b_l[nt] = *(const bf16x8*)&Bs[1][c * 32 + lk];
        }
#pragma unroll
        for (int mt = 0; mt < 4; ++mt)
#pragma unroll
            for (int nt = 0; nt < 4; ++nt) {
                acc[mt][nt] = __builtin_amdgcn_mfma_f32_16x16x32_bf16(a_h[mt], b_h[nt], acc[mt][nt], 0, 0, 0);
                acc[mt][nt] = __builtin_amdgcn_mfma_f32_16x16x32_bf16(a_h[mt], b_l[nt], acc[mt][nt], 0, 0, 0);
                acc[mt][nt] = __builtin_amdgcn_mfma_f32_16x16x32_bf16(a_l[mt], b_h[nt], acc[mt][nt], 0, 0, 0);
            }
    }

    const int crow = (lane >> 4) * 4;
#pragma unroll
    for (int mt = 0; mt < 4; ++mt)
#pragma unroll
        for (int nt = 0; nt < 4; ++nt) {
            const int cc = col0 + wn * 64 + nt * 16 + lr;
            if (cc < N) {
#pragma unroll
                for (int r = 0; r < 4; ++r)
                    C[(size_t)(row0 + wm * 64 + mt * 16 + crow + r) * ldc + cc] = acc[mt][nt][r];
            }
        }
}

// ---------------------------------------------------------------------------
// Depthwise causal conv (4 taps) + bias + SiLU + dt/dA precompute.
// ---------------------------------------------------------------------------
__global__ __launch_bounds__(320)
void conv_kernel(const float* __restrict__ zx,
                 const float* __restrict__ cw,
                 const float* __restrict__ cb,
                 const float* __restrict__ dtbias,
                 const float* __restrict__ alog,
                 float* __restrict__ xh,
                 float* __restrict__ Bb,
                 float* __restrict__ Cb,
                 float* __restrict__ dtb,
                 float* __restrict__ dAb)
{
    const int row = blockIdx.x;
    const int l   = row & (SEQ - 1);
    const int c4  = threadIdx.x * 4;

    float4 acc = *(const float4*)&cb[c4];
#pragma unroll
    for (int k = 0; k < DCONV; ++k) {
        const int lk = l - (DCONV - 1) + k;
        if (lk >= 0) {
            const float4 v = *(const float4*)&zx[(size_t)(row - (DCONV - 1) + k) * DINPROJ + DINNER + c4];
            const float4 w = *(const float4*)&cw[k * CONVDIM + c4];
            acc.x = fmaf(v.x, w.x, acc.x);
            acc.y = fmaf(v.y, w.y, acc.y);
            acc.z = fmaf(v.z, w.z, acc.z);
            acc.w = fmaf(v.w, w.w, acc.w);
        }
    }
    acc.x = silu_f(acc.x);
    acc.y = silu_f(acc.y);
    acc.z = silu_f(acc.z);
    acc.w = silu_f(acc.w);

    if (c4 < DINNER) {
        *(float4*)&xh[(size_t)row * DINNER + c4] = acc;
    } else if (c4 < DINNER + DSTATE) {
        *(float4*)&Bb[(size_t)row * DSTATE + (c4 - DINNER)] = acc;
    } else {
        *(float4*)&Cb[(size_t)row * DSTATE + (c4 - DINNER - DSTATE)] = acc;
    }

    if (threadIdx.x < NHEADS) {
        const int hh = threadIdx.x;
        const float raw = zx[(size_t)row * DINPROJ + (DINNER + CONVDIM) + hh] + dtbias[hh];
        const float dtv = (raw > 20.0f) ? raw : log1pf(expf(raw));
        const float a = expf(alog[hh]);
        dtb[row * NHEADS + hh] = dtv;
        dAb[row * NHEADS + hh] = expf(-a * dtv);
    }
}

// ---------------------------------------------------------------------------
// Pass 1: local scan per (b,h,seg,half). One wave; hs[64]; h0 = 0.
// LDS-staged B/x/dA/dt per 8-step chunk with register prefetch.
// ---------------------------------------------------------------------------
__global__ __launch_bounds__(64, 4)
void scan_local(const float* __restrict__ xh,
                const float* __restrict__ Bb,
                const float* __restrict__ dtb,
                const float* __restrict__ dAb,
                float* __restrict__ hloc,   // (b,h,seg) x (128n x 64p)
                float* __restrict__ ptot)   // (b,h,seg)
{
    const int bid  = blockIdx.x;
    const int half = bid & 1;
    const int seg  = (bid >> 1) & (NSEG - 1);
    const int h    = (bid >> 6) & (NHEADS - 1);
    const int b    = bid >> 10;
    const int lane = threadIdx.x;

    __shared__ float Bs[CH * 64];
    __shared__ float xs[CH * 64];
    __shared__ float dAs[CH];
    __shared__ float dts[CH];

    float hs[64];
#pragma unroll
    for (int j = 0; j < 64; ++j) hs[j] = 0.0f;
    float prun = 1.0f;

    const size_t row0 = (size_t)b * SEQ + (size_t)seg * TSEG;
    const float* __restrict__ Bp  = Bb  + row0 * DSTATE + half * 64;
    const float* __restrict__ xp  = xh  + row0 * DINNER + h * HEADDIM;
    const float* __restrict__ dAp = dAb + row0 * NHEADS + h;
    const float* __restrict__ dtp = dtb + row0 * NHEADS + h;

    const int i0 = lane, i1 = lane + 64;   // float4 slots within the chunk
    float4 rb0, rb1, rx0, rx1;
    float rsc = 0.0f;                       // dA (lanes 0..7) / dt (8..15)

    // prefetch chunk 0
    {
        const int t0 = 0;
        rb0 = *(const float4*)&Bp[(size_t)(t0 + (i0 >> 4)) * DSTATE + (i0 & 15) * 4];
        rb1 = *(const float4*)&Bp[(size_t)(t0 + (i1 >> 4)) * DSTATE + (i1 & 15) * 4];
        rx0 = *(const float4*)&xp[(size_t)(t0 + (i0 >> 4)) * DINNER + (i0 & 15) * 4];
        rx1 = *(const float4*)&xp[(size_t)(t0 + (i1 >> 4)) * DINNER + (i1 & 15) * 4];
        if (lane < CH)            rsc = dAp[(size_t)(t0 + lane) * NHEADS];
        else if (lane < 2 * CH)   rsc = dtp[(size_t)(t0 + lane - CH) * NHEADS];
    }

    for (int c = 0; c < NCH; ++c) {
        // write staged regs to LDS (single-wave block: DS ops in order, no barrier)
        *(float4*)&Bs[i0 * 4] = rb0;  *(float4*)&Bs[i1 * 4] = rb1;
        *(float4*)&xs[i0 * 4] = rx0;  *(float4*)&xs[i1 * 4] = rx1;
        if (lane < CH)            dAs[lane] = rsc;
        else if (lane < 2 * CH)   dts[lane - CH] = rsc;

        // prefetch next chunk
        if (c + 1 < NCH) {
            const int t0 = (c + 1) * CH;
            rb0 = *(const float4*)&Bp[(size_t)(t0 + (i0 >> 4)) * DSTATE + (i0 & 15) * 4];
            rb1 = *(const float4*)&Bp[(size_t)(t0 + (i1 >> 4)) * DSTATE + (i1 & 15) * 4];
            rx0 = *(const float4*)&xp[(size_t)(t0 + (i0 >> 4)) * DINNER + (i0 & 15) * 4];
            rx1 = *(const float4*)&xp[(size_t)(t0 + (i1 >> 4)) * DINNER + (i1 & 15) * 4];
            if (lane < CH)            rsc = dAp[(size_t)(t0 + lane) * NHEADS];
            else if (lane < 2 * CH)   rsc = dtp[(size_t)(t0 + lane - CH) * NHEADS];
        }

#pragma unroll
        for (int ts = 0; ts < CH; ++ts) {
            const float dA  = dAs[ts];
            const float dtx = dts[ts] * xs[ts * 64 + lane];
            prun *= dA;
#pragma unroll
            for (int j4 = 0; j4 < 16; ++j4) {
                const float4 b4 = *(const float4*)&Bs[ts * 64 + j4 * 4];
                hs[j4 * 4 + 0] = fmaf(dA, hs[j4 * 4 + 0], dtx * b4.x);
                hs[j4 * 4 + 1] = fmaf(dA, hs[j4 * 4 + 1], dtx * b4.y);
                hs[j4 * 4 + 2] = fmaf(dA, hs[j4 * 4 + 2], dtx * b4.z);
                hs[j4 * 4 + 3] = fmaf(dA, hs[j4 * 4 + 3], dtx * b4.w);
            }
        }
    }

    const size_t sidx = (size_t)((b * NHEADS + h) * NSEG + seg) * (DSTATE * HEADDIM);
#pragma unroll
    for (int j = 0; j < 64; ++j)
        hloc[sidx + (size_t)(half * 64 + j) * HEADDIM + lane] = hs[j];
    if (half == 0 && lane == 0)
        ptot[(b * NHEADS + h) * NSEG + seg] = prun;
}

// ---------------------------------------------------------------------------
// Pass 2: sequential combine over 32 segments (in-place: hloc becomes h0).
// ---------------------------------------------------------------------------
__global__ __launch_bounds__(256)
void combine_kernel(float* __restrict__ hloc,
                    const float* __restrict__ ptot)
{
    const int bid = blockIdx.x;
    const int bh = bid >> 3;
    const int chunk = bid & 7;
    const int e0 = chunk * 1024 + threadIdx.x * 4;

    float4 s = make_float4(0.f, 0.f, 0.f, 0.f);
    for (int k = 0; k < NSEG; ++k) {
        float* p = &hloc[((size_t)bh * NSEG + k) * (DSTATE * HEADDIM) + e0];
        const float4 v = *(const float4*)p;
        *(float4*)p = s;
        const float pt = ptot[bh * NSEG + k];
        s.x = fmaf(pt, s.x, v.x);
        s.y = fmaf(pt, s.y, v.y);
        s.z = fmaf(pt, s.z, v.z);
        s.w = fmaf(pt, s.w, v.w);
    }
}

// ---------------------------------------------------------------------------
// Pass 3: full scan per (b,h,seg,half) with true h0; atomicAdd y halves.
// ---------------------------------------------------------------------------
__global__ __launch_bounds__(64, 4)
void scan_full(const float* __restrict__ xh,
               const float* __restrict__ Bb,
               const float* __restrict__ Cb,
               const float* __restrict__ dtb,
               const float* __restrict__ dAb,
               const float* __restrict__ h0,    // (b,h,seg) x (128n x 64p)
               float* __restrict__ yb)          // (rows, 1024) zero-initialized
{
    const int bid  = blockIdx.x;
    const int half = bid & 1;
    const int seg  = (bid >> 1) & (NSEG - 1);
    const int h    = (bid >> 6) & (NHEADS - 1);
    const int b    = bid >> 10;
    const int lane = threadIdx.x;

    __shared__ float Bs[CH * 64];
    __shared__ float Cs[CH * 64];
    __shared__ float xs[CH * 64];
    __shared__ float dAs[CH];
    __shared__ float dts[CH];

    const size_t sidx = (size_t)((b * NHEADS + h) * NSEG + seg) * (DSTATE * HEADDIM);
    float hs[64];
#pragma unroll
    for (int j = 0; j < 64; ++j)
        hs[j] = h0[sidx + (size_t)(half * 64 + j) * HEADDIM + lane];

    const size_t row0 = (size_t)b * SEQ + (size_t)seg * TSEG;
    const float* __restrict__ Bp  = Bb  + row0 * DSTATE + half * 64;
    const float* __restrict__ Cp  = Cb  + row0 * DSTATE + half * 64;
    const float* __restrict__ xp  = xh  + row0 * DINNER + h * HEADDIM;
    const float* __restrict__ dAp = dAb + row0 * NHEADS + h;
    const float* __restrict__ dtp = dtb + row0 * NHEADS + h;
    float* __restrict__ yo = yb + row0 * DINNER + h * HEADDIM + lane;

    const int i0 = lane, i1 = lane + 64;
    float4 rb0, rb1, rc0, rc1, rx0, rx1;
    float rsc = 0.0f;

    {
        const int t0 = 0;
        rb0 = *(const float4*)&Bp[(size_t)(t0 + (i0 >> 4)) * DSTATE + (i0 & 15) * 4];
        rb1 = *(const float4*)&Bp[(size_t)(t0 + (i1 >> 4)) * DSTATE + (i1 & 15) * 4];
        rc0 = *(const float4*)&Cp[(size_t)(t0 + (i0 >> 4)) * DSTATE + (i0 & 15) * 4];
        rc1 = *(const float4*)&Cp[(size_t)(t0 + (i1 >> 4)) * DSTATE + (i1 & 15) * 4];
        rx0 = *(const float4*)&xp[(size_t)(t0 + (i0 >> 4)) * DINNER + (i0 & 15) * 4];
        rx1 = *(const float4*)&xp[(size_t)(t0 + (i1 >> 4)) * DINNER + (i1 & 15) * 4];
        if (lane < CH)            rsc = dAp[(size_t)(t0 + lane) * NHEADS];
        else if (lane < 2 * CH)   rsc = dtp[(size_t)(t0 + lane - CH) * NHEADS];
    }

    for (int c = 0; c < NCH; ++c) {
        *(float4*)&Bs[i0 * 4] = rb0;  *(float4*)&Bs[i1 * 4] = rb1;
        *(float4*)&Cs[i0 * 4] = rc0;  *(float4*)&Cs[i1 * 4] = rc1;
        *(float4*)&xs[i0 * 4] = rx0;  *(float4*)&xs[i1 * 4] = rx1;
        if (lane < CH)            dAs[lane] = rsc;
        else if (lane < 2 * CH)   dts[lane - CH] = rsc;

        if (c + 1 < NCH) {
            const int t0 = (c + 1) * CH;
            rb0 = *(const float4*)&Bp[(size_t)(t0 + (i0 >> 4)) * DSTATE + (i0 & 15) * 4];
            rb1 = *(const float4*)&Bp[(size_t)(t0 + (i1 >> 4)) * DSTATE + (i1 & 15) * 4];
            rc0 = *(const float4*)&Cp[(size_t)(t0 + (i0 >> 4)) * DSTATE + (i0 & 15) * 4];
            rc1 = *(const float4*)&Cp[(size_t)(t0 + (i1 >> 4)) * DSTATE + (i1 & 15) * 4];
            rx0 = *(const float4*)&xp[(size_t)(t0 + (i0 >> 4)) * DINNER + (i0 & 15) * 4];
            rx1 = *(const float4*)&xp[(size_t)(t0 + (i1 >> 4)) * DINNER + (i1 & 15) * 4];
            if (lane < CH)            rsc = dAp[(size_t)(t0 + lane) * NHEADS];
            else if (lane < 2 * CH)   rsc = dtp[(size_t)(t0 + lane - CH) * NHEADS];
        }

#pragma unroll
        for (int ts = 0; ts < CH; ++ts) {
            const float dA  = dAs[ts];
            const float dtx = dts[ts] * xs[ts * 64 + lane];
            float y0 = 0.f, y1 = 0.f, y2 = 0.f, y3 = 0.f;
#pragma unroll
            for (int j4 = 0; j4 < 16; ++j4) {
                const float4 b4 = *(const float4*)&Bs[ts * 64 + j4 * 4];
                const float4 c4 = *(const float4*)&Cs[ts * 64 + j4 * 4];
                hs[j4 * 4 + 0] = fmaf(dA, hs[j4 * 4 + 0], dtx * b4.x);
                hs[j4 * 4 + 1] = fmaf(dA, hs[j4 * 4 + 1], dtx * b4.y);
                hs[j4 * 4 + 2] = fmaf(dA, hs[j4 * 4 + 2], dtx * b4.z);
                hs[j4 * 4 + 3] = fmaf(dA, hs[j4 * 4 + 3], dtx * b4.w);
                y0 = fmaf(hs[j4 * 4 + 0], c4.x, y0);
                y1 = fmaf(hs[j4 * 4 + 1], c4.y, y1);
                y2 = fmaf(hs[j4 * 4 + 2], c4.z, y2);
                y3 = fmaf(hs[j4 * 4 + 3], c4.w, y3);
            }
            atomicAdd(&yo[(size_t)(c * CH + ts) * DINNER], (y0 + y1) + (y2 + y3));
        }
    }
}

// ---------------------------------------------------------------------------
// Gate + D-skip + RMSNorm; writes ynorm as split-bf16 planes.
// ---------------------------------------------------------------------------
__global__ __launch_bounds__(256)
void gate_kernel(const float* __restrict__ yb,
                 const float* __restrict__ xh,
                 const float* __restrict__ dskip,
                 const float* __restrict__ zx,
                 const float* __restrict__ nw,
                 unsigned short* __restrict__ yh,
                 unsigned short* __restrict__ yl)
{
    const int row = blockIdx.x;
    const int c4 = threadIdx.x * 4;

    float4 y = *(const float4*)&yb[(size_t)row * DINNER + c4];
    const float4 xv = *(const float4*)&xh[(size_t)row * DINNER + c4];
    const float dsk = dskip[c4 >> 6];
    y.x = fmaf(dsk, xv.x, y.x);
    y.y = fmaf(dsk, xv.y, y.y);
    y.z = fmaf(dsk, xv.z, y.z);
    y.w = fmaf(dsk, xv.w, y.w);

    const float4 z = *(const float4*)&zx[(size_t)row * DINPROJ + c4];
    float4 g;
    g.x = y.x * silu_f(z.x);
    g.y = y.y * silu_f(z.y);
    g.z = y.z * silu_f(z.z);
    g.w = y.w * silu_f(z.w);

    float local = g.x * g.x + g.y * g.y + g.z * g.z + g.w * g.w;
#pragma unroll
    for (int m = 32; m >= 1; m >>= 1) local += __shfl_xor(local, m, 64);

    __shared__ float red[4];
    if ((threadIdx.x & 63) == 0) red[threadIdx.x >> 6] = local;
    __syncthreads();
    const float total = red[0] + red[1] + red[2] + red[3];
    const float scale = rsqrtf(total * (1.0f / (float)DINNER) + 1e-5f);

    const float4 w = *(const float4*)&nw[c4];
    float o[4];
    o[0] = g.x * scale * w.x;
    o[1] = g.y * scale * w.y;
    o[2] = g.z * scale * w.z;
    o[3] = g.w * scale * w.w;

    unsigned hv[4], lv[4];
#pragma unroll
    for (int j = 0; j < 4; ++j) {
        hv[j] = f2bfu(o[j]);
        lv[j] = f2bfu(o[j] - bfu2f((unsigned short)hv[j]));
    }
    const size_t oi = (size_t)row * DINNER + c4;
    *(uint2*)&yh[oi] = make_uint2(hv[0] | (hv[1] << 16), hv[2] | (hv[3] << 16));
    *(uint2*)&yl[oi] = make_uint2(lv[0] | (lv[1] << 16), lv[2] | (lv[3] << 16));
}

// ---------------------------------------------------------------------------
extern "C" void kernel_launch(void* const* d_in, const int* in_sizes, int n_in,
                              void* d_out, int out_size, void* d_ws, size_t ws_size,
                              hipStream_t stream)
{
    const float* x_in    = (const float*)d_in[0];
    const float* in_w    = (const float*)d_in[1];
    const float* conv_w  = (const float*)d_in[2];
    const float* conv_b  = (const float*)d_in[3];
    const float* dt_bias = (const float*)d_in[4];
    const float* A_log   = (const float*)d_in[5];
    const float* D_skip  = (const float*)d_in[6];
    const float* norm_w  = (const float*)d_in[7];
    const float* out_w   = (const float*)d_in[8];
    float* out = (float*)d_out;

    float* ws   = (float*)d_ws;
    float* zx   = ws;                               // 19,005,440 f
    float* xh   = zx   + (size_t)ROWS * DINPROJ;    //  8,388,608 f
    float* Bb   = xh   + (size_t)ROWS * DINNER;     //  1,048,576 f
    float* Cb   = Bb   + (size_t)ROWS * DSTATE;     //  1,048,576 f
    float* dtb  = Cb   + (size_t)ROWS * DSTATE;     //    131,072 f
    float* dAb  = dtb  + (size_t)ROWS * NHEADS;     //    131,072 f
    float* yb   = dAb  + (size_t)ROWS * NHEADS;     //  8,388,608 f
    float* UN   = yb   + (size_t)ROWS * DINNER;     // 16,777,216 f (union)
    float* BtF  = UN   + (size_t)16777216;          //  1,245,184 f
    float* WtF  = BtF  + (size_t)1245184;           //    524,288 f
    float* ptot = WtF  + (size_t)524288;            //      2,048 f

    unsigned short* Ah = (unsigned short*)UN;                 // [8192][512]
    unsigned short* Al = Ah + (size_t)ROWS * DMODEL;
    float*          hloc = UN;                                // 16.78M f
    unsigned short* yh = (unsigned short*)UN;                 // [8192][1024]
    unsigned short* yl = yh + (size_t)ROWS * DINNER;

    unsigned short* Bth = (unsigned short*)BtF;               // [2432][512]
    unsigned short* Btl = Bth + (size_t)NPAD_IN * DMODEL;
    unsigned short* Wth = (unsigned short*)WtF;               // [512][1024]
    unsigned short* Wtl = Wth + (size_t)DMODEL * DINNER;

    for (int layer = 0; layer < 2; ++layer) {
        const float* xl = (layer == 0) ? x_in : out;

        split_a_kernel<<<(ROWS * DMODEL) / (256 * 8), 256, 0, stream>>>(xl, Ah, Al);

        tsplit_w_kernel<<<dim3(NPAD_IN / 32, DMODEL / 32), 256, 0, stream>>>(
            in_w + (size_t)layer * DMODEL * DINPROJ, DMODEL, DINPROJ, Bth, Btl);

        gemm_bf16s<<<dim3(NPAD_IN / 128, ROWS / 128), 256, 0, stream>>>(
            Ah, Al, Bth, Btl, zx, DINPROJ, DINPROJ, DMODEL);

        conv_kernel<<<ROWS, CONVDIM / 4, 0, stream>>>(
            zx,
            conv_w + (size_t)layer * DCONV * CONVDIM,
            conv_b + (size_t)layer * CONVDIM,
            dt_bias + (size_t)layer * NHEADS,
            A_log + (size_t)layer * NHEADS,
            xh, Bb, Cb, dtb, dAb);

        zero_kernel<<<(ROWS * DINNER) / (256 * 16), 256, 0, stream>>>(yb);

        scan_local<<<BATCH * NHEADS * NSEG * 2, 64, 0, stream>>>(
            xh, Bb, dtb, dAb, hloc, ptot);

        combine_kernel<<<BATCH * NHEADS * 8, 256, 0, stream>>>(hloc, ptot);

        scan_full<<<BATCH * NHEADS * NSEG * 2, 64, 0, stream>>>(
            xh, Bb, Cb, dtb, dAb, hloc, yb);

        gate_kernel<<<ROWS, 256, 0, stream>>>(
            yb, xh, D_skip + (size_t)layer * NHEADS,
            zx, norm_w + (size_t)layer * DINNER, yh, yl);

        tsplit_w_kernel<<<dim3(DMODEL / 32, DINNER / 32), 256, 0, stream>>>(
            out_w + (size_t)layer * DINNER * DMODEL, DINNER, DMODEL, Wth, Wtl);

        gemm_bf16s<<<dim3(DMODEL / 128, ROWS / 128), 256, 0, stream>>>(
            yh, yl, Wth, Wtl, out, DMODEL, DMODEL, DINNER);
    }
}

// Round 6
// 792.458 us; speedup vs baseline: 5.6050x; 1.2063x over previous
//
#include <hip/hip_runtime.h>
#include <hip/hip_bf16.h>
#include <cstddef>
#include <cstdint>

// Mamba2 (2 layers). GEMMs via split-bf16 MFMA (C = AhBh + AhBl + AlBh),
// segmented-parallel selective scan (NSEG=32). Scan blocks: 128 threads
// (2 waves), wave w owns n-half, hs[64]/lane; LDS-staged B/C/x (double-
// buffered, 1 barrier per 8-step chunk); y halves merged via LDS (no atomics).
//
// Workspace (floats): zx 19.0M | xh 8.39M | Bb 1.05M | Cb 1.05M | dtb .13M |
// dAb .13M | yb 8.39M | UNION 16.78M {Ah/Al | hloc | yh/yl} | Bt 1.25M |
// Wt 0.52M | ptot 2k  => 226.8 MB (budget: 253 MB proven safe).

#define BATCH 4
#define SEQ   2048
#define DMODEL 512
#define DINNER 1024
#define DSTATE 128
#define HEADDIM 64
#define NHEADS 16
#define DCONV 4
#define CONVDIM 1280
#define DINPROJ 2320
#define NPAD_IN 2432          // 19 * 128
#define ROWS (BATCH * SEQ)    // 8192
#define NSEG 32
#define TSEG 64               // SEQ / NSEG
#define CH 8                  // steps staged per LDS chunk
#define NCH (TSEG / CH)       // 8 chunks per segment

typedef __attribute__((ext_vector_type(8))) short bf16x8;
typedef __attribute__((ext_vector_type(4))) float f32x4;

__device__ __forceinline__ float silu_f(float x) {
    return x * (1.0f / (1.0f + __expf(-x)));
}
__device__ __forceinline__ unsigned short f2bfu(float f) {  // RNE fp32->bf16
    unsigned u = __float_as_uint(f);
    unsigned r = u + 0x7FFFu + ((u >> 16) & 1u);
    return (unsigned short)(r >> 16);
}
__device__ __forceinline__ float bfu2f(unsigned short h) {
    return __uint_as_float(((unsigned)h) << 16);
}

// ---------------------------------------------------------------------------
// Split fp32 A[M*K] -> Ah, Al (bf16). 8 elems/thread.
// ---------------------------------------------------------------------------
__global__ __launch_bounds__(256)
void split_a_kernel(const float* __restrict__ A,
                    unsigned short* __restrict__ Ah,
                    unsigned short* __restrict__ Al)
{
    const size_t i = ((size_t)blockIdx.x * 256 + threadIdx.x) * 8;
    const float4 a = *(const float4*)&A[i];
    const float4 b = *(const float4*)&A[i + 4];
    float v[8] = {a.x, a.y, a.z, a.w, b.x, b.y, b.z, b.w};
    unsigned hv[8], lv[8];
#pragma unroll
    for (int j = 0; j < 8; ++j) {
        hv[j] = f2bfu(v[j]);
        lv[j] = f2bfu(v[j] - bfu2f((unsigned short)hv[j]));
    }
    uint4 ph = make_uint4(hv[0] | (hv[1] << 16), hv[2] | (hv[3] << 16),
                          hv[4] | (hv[5] << 16), hv[6] | (hv[7] << 16));
    uint4 pl = make_uint4(lv[0] | (lv[1] << 16), lv[2] | (lv[3] << 16),
                          lv[4] | (lv[5] << 16), lv[6] | (lv[7] << 16));
    *(uint4*)&Ah[i] = ph;
    *(uint4*)&Al[i] = pl;
}

// ---------------------------------------------------------------------------
// Transpose + split weight W[K][N] fp32 -> Oh/Ol[Npad][K] bf16 (n >= N -> 0).
// ---------------------------------------------------------------------------
__global__ __launch_bounds__(256)
void tsplit_w_kernel(const float* __restrict__ W, int K, int N,
                     unsigned short* __restrict__ Oh,
                     unsigned short* __restrict__ Ol)
{
    __shared__ float tile[32][33];
    const int n0 = blockIdx.x * 32, k0 = blockIdx.y * 32;
    const int c = threadIdx.x & 31, r8 = threadIdx.x >> 5;
    const int n = n0 + c;
#pragma unroll
    for (int i = 0; i < 4; ++i) {
        const int k = r8 + i * 8;
        float v = 0.0f;
        if (n < N) v = W[(size_t)(k0 + k) * N + n];
        tile[c][k] = v;
    }
    __syncthreads();
#pragma unroll
    for (int i = 0; i < 4; ++i) {
        const int nl = r8 + i * 8;
        const float v = tile[nl][c];
        const unsigned short h = f2bfu(v);
        const unsigned short l = f2bfu(v - bfu2f(h));
        const size_t o = (size_t)(n0 + nl) * K + k0 + c;
        Oh[o] = h;
        Ol[o] = l;
    }
}

// ---------------------------------------------------------------------------
// Split-bf16 MFMA GEMM (unchanged, passing).
// ---------------------------------------------------------------------------
__global__ __launch_bounds__(256)
void gemm_bf16s(const unsigned short* __restrict__ Ah,
                const unsigned short* __restrict__ Al,
                const unsigned short* __restrict__ Bh,
                const unsigned short* __restrict__ Bl,
                float* __restrict__ C, int ldc, int N, int K)
{
    __shared__ __align__(16) unsigned short As[2][128 * 32];
    __shared__ __align__(16) unsigned short Bs[2][128 * 32];

    const int tid = threadIdx.x;
    const int w = tid >> 6, lane = tid & 63;
    const int wm = w >> 1, wn = w & 1;
    const int row0 = blockIdx.y * 128, col0 = blockIdx.x * 128;

    const int srow = tid >> 1;
    const int sk   = (tid & 1) * 16;

    const int lr = lane & 15;
    const int lk = (lane >> 4) * 8;

    f32x4 acc[4][4];
#pragma unroll
    for (int i = 0; i < 4; ++i)
#pragma unroll
        for (int j = 0; j < 4; ++j) acc[i][j] = (f32x4){0.f, 0.f, 0.f, 0.f};

    for (int k0 = 0; k0 < K; k0 += 32) {
        const size_t ga = (size_t)(row0 + srow) * K + k0 + sk;
        const size_t gb = (size_t)(col0 + srow) * K + k0 + sk;
        const uint4 vah0 = *(const uint4*)&Ah[ga];
        const uint4 vah1 = *(const uint4*)&Ah[ga + 8];
        const uint4 val0 = *(const uint4*)&Al[ga];
        const uint4 val1 = *(const uint4*)&Al[ga + 8];
        const uint4 vbh0 = *(const uint4*)&Bh[gb];
        const uint4 vbh1 = *(const uint4*)&Bh[gb + 8];
        const uint4 vbl0 = *(const uint4*)&Bl[gb];
        const uint4 vbl1 = *(const uint4*)&Bl[gb + 8];
        __syncthreads();
        const int so = srow * 32 + sk;
        *(uint4*)&As[0][so] = vah0;  *(uint4*)&As[0][so + 8] = vah1;
        *(uint4*)&As[1][so] = val0;  *(uint4*)&As[1][so + 8] = val1;
        *(uint4*)&Bs[0][so] = vbh0;  *(uint4*)&Bs[0][so + 8] = vbh1;
        *(uint4*)&Bs[1][so] = vbl0;  *(uint4*)&Bs[1][so + 8] = vbl1;
        __syncthreads();

        bf16x8 a_h[4], a_l[4], b_h[4], b_l[4];
#pragma unroll
        for (int mt = 0; mt < 4; ++mt) {
            const int r = wm * 64 + mt * 16 + lr;
            a_h[mt] = *(const bf16x8*)&As[0][r * 32 + lk];
            a_l[mt] = *(const bf16x8*)&As[1][r * 32 + lk];
        }
#pragma unroll
        for (int nt = 0; nt < 4; ++nt) {
            const int c = wn * 64 + nt * 16 + lr;
            b_h[nt] = *(const bf16x8*)&Bs[0][c * 32 + lk];
            b_l[nt] = *(const bf16x8*)&Bs[1][c * 32 + lk];
        }
#pragma unroll
        for (int mt = 0; mt < 4; ++mt)
#pragma unroll
            for (int nt = 0; nt < 4; ++nt) {
                acc[mt][nt] = __builtin_amdgcn_mfma_f32_16x16x32_bf16(a_h[mt], b_h[nt], acc[mt][nt], 0, 0, 0);
                acc[mt][nt] = __builtin_amdgcn_mfma_f32_16x16x32_bf16(a_h[mt], b_l[nt], acc[mt][nt], 0, 0, 0);
                acc[mt][nt] = __builtin_amdgcn_mfma_f32_16x16x32_bf16(a_l[mt], b_h[nt], acc[mt][nt], 0, 0, 0);
            }
    }

    const int crow = (lane >> 4) * 4;
#pragma unroll
    for (int mt = 0; mt < 4; ++mt)
#pragma unroll
        for (int nt = 0; nt < 4; ++nt) {
            const int cc = col0 + wn * 64 + nt * 16 + lr;
            if (cc < N) {
#pragma unroll
                for (int r = 0; r < 4; ++r)
                    C[(size_t)(row0 + wm * 64 + mt * 16 + crow + r) * ldc + cc] = acc[mt][nt][r];
            }
        }
}

// ---------------------------------------------------------------------------
// Depthwise causal conv (4 taps) + bias + SiLU + dt/dA precompute.
// ---------------------------------------------------------------------------
__global__ __launch_bounds__(320)
void conv_kernel(const float* __restrict__ zx,
                 const float* __restrict__ cw,
                 const float* __restrict__ cb,
                 const float* __restrict__ dtbias,
                 const float* __restrict__ alog,
                 float* __restrict__ xh,
                 float* __restrict__ Bb,
                 float* __restrict__ Cb,
                 float* __restrict__ dtb,
                 float* __restrict__ dAb)
{
    const int row = blockIdx.x;
    const int l   = row & (SEQ - 1);
    const int c4  = threadIdx.x * 4;

    float4 acc = *(const float4*)&cb[c4];
#pragma unroll
    for (int k = 0; k < DCONV; ++k) {
        const int lk = l - (DCONV - 1) + k;
        if (lk >= 0) {
            const float4 v = *(const float4*)&zx[(size_t)(row - (DCONV - 1) + k) * DINPROJ + DINNER + c4];
            const float4 w = *(const float4*)&cw[k * CONVDIM + c4];
            acc.x = fmaf(v.x, w.x, acc.x);
            acc.y = fmaf(v.y, w.y, acc.y);
            acc.z = fmaf(v.z, w.z, acc.z);
            acc.w = fmaf(v.w, w.w, acc.w);
        }
    }
    acc.x = silu_f(acc.x);
    acc.y = silu_f(acc.y);
    acc.z = silu_f(acc.z);
    acc.w = silu_f(acc.w);

    if (c4 < DINNER) {
        *(float4*)&xh[(size_t)row * DINNER + c4] = acc;
    } else if (c4 < DINNER + DSTATE) {
        *(float4*)&Bb[(size_t)row * DSTATE + (c4 - DINNER)] = acc;
    } else {
        *(float4*)&Cb[(size_t)row * DSTATE + (c4 - DINNER - DSTATE)] = acc;
    }

    if (threadIdx.x < NHEADS) {
        const int hh = threadIdx.x;
        const float raw = zx[(size_t)row * DINPROJ + (DINNER + CONVDIM) + hh] + dtbias[hh];
        const float dtv = (raw > 20.0f) ? raw : log1pf(expf(raw));
        const float a = expf(alog[hh]);
        dtb[row * NHEADS + hh] = dtv;
        dAb[row * NHEADS + hh] = expf(-a * dtv);
    }
}

// ---------------------------------------------------------------------------
// Pass 1: local scan per (b,h,seg). 128 threads (2 waves); wave w owns
// n in [64w, 64w+64); hs[64]/lane; h0 = 0. B/x LDS double-buffered.
// ---------------------------------------------------------------------------
__global__ __launch_bounds__(128, 2)
void scan_local(const float* __restrict__ xh,
                const float* __restrict__ Bb,
                const float* __restrict__ dtb,
                const float* __restrict__ dAb,
                float* __restrict__ hloc,   // (b,h,seg) x (128n x 64p)
                float* __restrict__ ptot)   // (b,h,seg)
{
    const int bid  = blockIdx.x;
    const int seg  = bid & (NSEG - 1);
    const int h    = (bid >> 5) & (NHEADS - 1);
    const int b    = bid >> 9;
    const int tid  = threadIdx.x;
    const int w    = tid >> 6;
    const int lane = tid & 63;

    __shared__ float Bs[2][CH * 128];
    __shared__ float xs[2][CH * 64];
    __shared__ float dAs[2][CH];
    __shared__ float dts[2][CH];

    float hs[64];
#pragma unroll
    for (int j = 0; j < 64; ++j) hs[j] = 0.0f;
    float prun = 1.0f;

    const size_t row0 = (size_t)b * SEQ + (size_t)seg * TSEG;
    const float* __restrict__ Bp  = Bb  + row0 * DSTATE;
    const float* __restrict__ xp  = xh  + row0 * DINNER + h * HEADDIM;
    const float* __restrict__ dAp = dAb + row0 * NHEADS + h;
    const float* __restrict__ dtp = dtb + row0 * NHEADS + h;

    const int sB0 = tid, sB1 = tid + 128;   // B float4 slots (256/chunk)
    const int sX  = tid;                     // x float4 slots (128/chunk)

    float4 rb0, rb1, rx;
    float rsc = 0.0f;

    {   // prefetch chunk 0
        rb0 = *(const float4*)&Bp[(size_t)(sB0 >> 5) * DSTATE + (sB0 & 31) * 4];
        rb1 = *(const float4*)&Bp[(size_t)(sB1 >> 5) * DSTATE + (sB1 & 31) * 4];
        rx  = *(const float4*)&xp[(size_t)(sX >> 4) * DINNER + (sX & 15) * 4];
        if (tid < CH)            rsc = dAp[(size_t)tid * NHEADS];
        else if (tid < 2 * CH)   rsc = dtp[(size_t)(tid - CH) * NHEADS];
    }

    for (int c = 0; c < NCH; ++c) {
        const int cur = c & 1;
        *(float4*)&Bs[cur][sB0 * 4] = rb0;
        *(float4*)&Bs[cur][sB1 * 4] = rb1;
        *(float4*)&xs[cur][sX * 4]  = rx;
        if (tid < CH)            dAs[cur][tid] = rsc;
        else if (tid < 2 * CH)   dts[cur][tid - CH] = rsc;
        __syncthreads();

        if (c + 1 < NCH) {
            const int t0 = (c + 1) * CH;
            rb0 = *(const float4*)&Bp[(size_t)(t0 + (sB0 >> 5)) * DSTATE + (sB0 & 31) * 4];
            rb1 = *(const float4*)&Bp[(size_t)(t0 + (sB1 >> 5)) * DSTATE + (sB1 & 31) * 4];
            rx  = *(const float4*)&xp[(size_t)(t0 + (sX >> 4)) * DINNER + (sX & 15) * 4];
            if (tid < CH)            rsc = dAp[(size_t)(t0 + tid) * NHEADS];
            else if (tid < 2 * CH)   rsc = dtp[(size_t)(t0 + tid - CH) * NHEADS];
        }

#pragma unroll
        for (int ts = 0; ts < CH; ++ts) {
            const float dA  = dAs[cur][ts];
            const float dtx = dts[cur][ts] * xs[cur][ts * 64 + lane];
            prun *= dA;
#pragma unroll
            for (int j4 = 0; j4 < 16; ++j4) {
                const float4 b4 = *(const float4*)&Bs[cur][ts * 128 + w * 64 + j4 * 4];
                hs[j4 * 4 + 0] = fmaf(dA, hs[j4 * 4 + 0], dtx * b4.x);
                hs[j4 * 4 + 1] = fmaf(dA, hs[j4 * 4 + 1], dtx * b4.y);
                hs[j4 * 4 + 2] = fmaf(dA, hs[j4 * 4 + 2], dtx * b4.z);
                hs[j4 * 4 + 3] = fmaf(dA, hs[j4 * 4 + 3], dtx * b4.w);
            }
        }
    }

    const size_t sidx = (size_t)((b * NHEADS + h) * NSEG + seg) * (DSTATE * HEADDIM);
#pragma unroll
    for (int j = 0; j < 64; ++j)
        hloc[sidx + (size_t)(w * 64 + j) * HEADDIM + lane] = hs[j];
    if (tid == 0)
        ptot[(b * NHEADS + h) * NSEG + seg] = prun;
}

// ---------------------------------------------------------------------------
// Pass 2: sequential combine over 32 segments (in-place: hloc becomes h0).
// ---------------------------------------------------------------------------
__global__ __launch_bounds__(256)
void combine_kernel(float* __restrict__ hloc,
                    const float* __restrict__ ptot)
{
    const int bid = blockIdx.x;
    const int bh = bid >> 3;
    const int chunk = bid & 7;
    const int e0 = chunk * 1024 + threadIdx.x * 4;

    float4 s = make_float4(0.f, 0.f, 0.f, 0.f);
    for (int k = 0; k < NSEG; ++k) {
        float* p = &hloc[((size_t)bh * NSEG + k) * (DSTATE * HEADDIM) + e0];
        const float4 v = *(const float4*)p;
        *(float4*)p = s;
        const float pt = ptot[bh * NSEG + k];
        s.x = fmaf(pt, s.x, v.x);
        s.y = fmaf(pt, s.y, v.y);
        s.z = fmaf(pt, s.z, v.z);
        s.w = fmaf(pt, s.w, v.w);
    }
}

// ---------------------------------------------------------------------------
// Pass 3: full scan per (b,h,seg), true h0. 2 waves split n; per-chunk y
// partials merged via LDS and stored plain (no atomics). Pipelined merge:
// chunk c-1 is stored right after the barrier of chunk c.
// ---------------------------------------------------------------------------
__global__ __launch_bounds__(128, 2)
void scan_full(const float* __restrict__ xh,
               const float* __restrict__ Bb,
               const float* __restrict__ Cb,
               const float* __restrict__ dtb,
               const float* __restrict__ dAb,
               const float* __restrict__ h0,    // (b,h,seg) x (128n x 64p)
               float* __restrict__ yb)          // (rows, 1024)
{
    const int bid  = blockIdx.x;
    const int seg  = bid & (NSEG - 1);
    const int h    = (bid >> 5) & (NHEADS - 1);
    const int b    = bid >> 9;
    const int tid  = threadIdx.x;
    const int w    = tid >> 6;
    const int lane = tid & 63;

    __shared__ float Bs[2][CH * 128];
    __shared__ float Cs[2][CH * 128];
    __shared__ float xs[2][CH * 64];
    __shared__ float ys[2][2][CH * 64];
    __shared__ float dAs[2][CH];
    __shared__ float dts[2][CH];

    const size_t sidx = (size_t)((b * NHEADS + h) * NSEG + seg) * (DSTATE * HEADDIM);
    float hs[64];
#pragma unroll
    for (int j = 0; j < 64; ++j)
        hs[j] = h0[sidx + (size_t)(w * 64 + j) * HEADDIM + lane];

    const size_t row0 = (size_t)b * SEQ + (size_t)seg * TSEG;
    const float* __restrict__ Bp  = Bb  + row0 * DSTATE;
    const float* __restrict__ Cp  = Cb  + row0 * DSTATE;
    const float* __restrict__ xp  = xh  + row0 * DINNER + h * HEADDIM;
    const float* __restrict__ dAp = dAb + row0 * NHEADS + h;
    const float* __restrict__ dtp = dtb + row0 * NHEADS + h;
    float* __restrict__ yo = yb + row0 * DINNER + h * HEADDIM;

    const int sB0 = tid, sB1 = tid + 128;
    const int sX  = tid;

    float4 rb0, rb1, rc0, rc1, rx;
    float rsc = 0.0f;

    {   // prefetch chunk 0
        rb0 = *(const float4*)&Bp[(size_t)(sB0 >> 5) * DSTATE + (sB0 & 31) * 4];
        rb1 = *(const float4*)&Bp[(size_t)(sB1 >> 5) * DSTATE + (sB1 & 31) * 4];
        rc0 = *(const float4*)&Cp[(size_t)(sB0 >> 5) * DSTATE + (sB0 & 31) * 4];
        rc1 = *(const float4*)&Cp[(size_t)(sB1 >> 5) * DSTATE + (sB1 & 31) * 4];
        rx  = *(const float4*)&xp[(size_t)(sX >> 4) * DINNER + (sX & 15) * 4];
        if (tid < CH)            rsc = dAp[(size_t)tid * NHEADS];
        else if (tid < 2 * CH)   rsc = dtp[(size_t)(tid - CH) * NHEADS];
    }

    for (int c = 0; c < NCH; ++c) {
        const int cur = c & 1;
        *(float4*)&Bs[cur][sB0 * 4] = rb0;
        *(float4*)&Bs[cur][sB1 * 4] = rb1;
        *(float4*)&Cs[cur][sB0 * 4] = rc0;
        *(float4*)&Cs[cur][sB1 * 4] = rc1;
        *(float4*)&xs[cur][sX * 4]  = rx;
        if (tid < CH)            dAs[cur][tid] = rsc;
        else if (tid < 2 * CH)   dts[cur][tid - CH] = rsc;
        __syncthreads();

        // store merged y of chunk c-1 (ys[cur^1] complete & visible)
        if (c > 0) {
            const int pb = cur ^ 1;
            const float4 v0 = *(const float4*)&ys[pb][0][tid * 4];
            const float4 v1 = *(const float4*)&ys[pb][1][tid * 4];
            float4 o;
            o.x = v0.x + v1.x; o.y = v0.y + v1.y;
            o.z = v0.z + v1.z; o.w = v0.w + v1.w;
            *(float4*)&yo[(size_t)((c - 1) * CH + (tid >> 4)) * DINNER + (tid & 15) * 4] = o;
        }

        if (c + 1 < NCH) {
            const int t0 = (c + 1) * CH;
            rb0 = *(const float4*)&Bp[(size_t)(t0 + (sB0 >> 5)) * DSTATE + (sB0 & 31) * 4];
            rb1 = *(const float4*)&Bp[(size_t)(t0 + (sB1 >> 5)) * DSTATE + (sB1 & 31) * 4];
            rc0 = *(const float4*)&Cp[(size_t)(t0 + (sB0 >> 5)) * DSTATE + (sB0 & 31) * 4];
            rc1 = *(const float4*)&Cp[(size_t)(t0 + (sB1 >> 5)) * DSTATE + (sB1 & 31) * 4];
            rx  = *(const float4*)&xp[(size_t)(t0 + (sX >> 4)) * DINNER + (sX & 15) * 4];
            if (tid < CH)            rsc = dAp[(size_t)(t0 + tid) * NHEADS];
            else if (tid < 2 * CH)   rsc = dtp[(size_t)(t0 + tid - CH) * NHEADS];
        }

#pragma unroll
        for (int ts = 0; ts < CH; ++ts) {
            const float dA  = dAs[cur][ts];
            const float dtx = dts[cur][ts] * xs[cur][ts * 64 + lane];
            float y0 = 0.f, y1 = 0.f, y2 = 0.f, y3 = 0.f;
#pragma unroll
            for (int j4 = 0; j4 < 16; ++j4) {
                const float4 b4 = *(const float4*)&Bs[cur][ts * 128 + w * 64 + j4 * 4];
                const float4 c4 = *(const float4*)&Cs[cur][ts * 128 + w * 64 + j4 * 4];
                hs[j4 * 4 + 0] = fmaf(dA, hs[j4 * 4 + 0], dtx * b4.x);
                hs[j4 * 4 + 1] = fmaf(dA, hs[j4 * 4 + 1], dtx * b4.y);
                hs[j4 * 4 + 2] = fmaf(dA, hs[j4 * 4 + 2], dtx * b4.z);
                hs[j4 * 4 + 3] = fmaf(dA, hs[j4 * 4 + 3], dtx * b4.w);
                y0 = fmaf(hs[j4 * 4 + 0], c4.x, y0);
                y1 = fmaf(hs[j4 * 4 + 1], c4.y, y1);
                y2 = fmaf(hs[j4 * 4 + 2], c4.z, y2);
                y3 = fmaf(hs[j4 * 4 + 3], c4.w, y3);
            }
            ys[cur][w][ts * 64 + lane] = (y0 + y1) + (y2 + y3);
        }
    }

    __syncthreads();
    {   // store last chunk
        const int pb = (NCH - 1) & 1;
        const float4 v0 = *(const float4*)&ys[pb][0][tid * 4];
        const float4 v1 = *(const float4*)&ys[pb][1][tid * 4];
        float4 o;
        o.x = v0.x + v1.x; o.y = v0.y + v1.y;
        o.z = v0.z + v1.z; o.w = v0.w + v1.w;
        *(float4*)&yo[(size_t)((NCH - 1) * CH + (tid >> 4)) * DINNER + (tid & 15) * 4] = o;
    }
}

// ---------------------------------------------------------------------------
// Gate + D-skip + RMSNorm; writes ynorm as split-bf16 planes.
// ---------------------------------------------------------------------------
__global__ __launch_bounds__(256)
void gate_kernel(const float* __restrict__ yb,
                 const float* __restrict__ xh,
                 const float* __restrict__ dskip,
                 const float* __restrict__ zx,
                 const float* __restrict__ nw,
                 unsigned short* __restrict__ yh,
                 unsigned short* __restrict__ yl)
{
    const int row = blockIdx.x;
    const int c4 = threadIdx.x * 4;

    float4 y = *(const float4*)&yb[(size_t)row * DINNER + c4];
    const float4 xv = *(const float4*)&xh[(size_t)row * DINNER + c4];
    const float dsk = dskip[c4 >> 6];
    y.x = fmaf(dsk, xv.x, y.x);
    y.y = fmaf(dsk, xv.y, y.y);
    y.z = fmaf(dsk, xv.z, y.z);
    y.w = fmaf(dsk, xv.w, y.w);

    const float4 z = *(const float4*)&zx[(size_t)row * DINPROJ + c4];
    float4 g;
    g.x = y.x * silu_f(z.x);
    g.y = y.y * silu_f(z.y);
    g.z = y.z * silu_f(z.z);
    g.w = y.w * silu_f(z.w);

    float local = g.x * g.x + g.y * g.y + g.z * g.z + g.w * g.w;
#pragma unroll
    for (int m = 32; m >= 1; m >>= 1) local += __shfl_xor(local, m, 64);

    __shared__ float red[4];
    if ((threadIdx.x & 63) == 0) red[threadIdx.x >> 6] = local;
    __syncthreads();
    const float total = red[0] + red[1] + red[2] + red[3];
    const float scale = rsqrtf(total * (1.0f / (float)DINNER) + 1e-5f);

    const float4 w = *(const float4*)&nw[c4];
    float o[4];
    o[0] = g.x * scale * w.x;
    o[1] = g.y * scale * w.y;
    o[2] = g.z * scale * w.z;
    o[3] = g.w * scale * w.w;

    unsigned hv[4], lv[4];
#pragma unroll
    for (int j = 0; j < 4; ++j) {
        hv[j] = f2bfu(o[j]);
        lv[j] = f2bfu(o[j] - bfu2f((unsigned short)hv[j]));
    }
    const size_t oi = (size_t)row * DINNER + c4;
    *(uint2*)&yh[oi] = make_uint2(hv[0] | (hv[1] << 16), hv[2] | (hv[3] << 16));
    *(uint2*)&yl[oi] = make_uint2(lv[0] | (lv[1] << 16), lv[2] | (lv[3] << 16));
}

// ---------------------------------------------------------------------------
extern "C" void kernel_launch(void* const* d_in, const int* in_sizes, int n_in,
                              void* d_out, int out_size, void* d_ws, size_t ws_size,
                              hipStream_t stream)
{
    const float* x_in    = (const float*)d_in[0];
    const float* in_w    = (const float*)d_in[1];
    const float* conv_w  = (const float*)d_in[2];
    const float* conv_b  = (const float*)d_in[3];
    const float* dt_bias = (const float*)d_in[4];
    const float* A_log   = (const float*)d_in[5];
    const float* D_skip  = (const float*)d_in[6];
    const float* norm_w  = (const float*)d_in[7];
    const float* out_w   = (const float*)d_in[8];
    float* out = (float*)d_out;

    float* ws   = (float*)d_ws;
    float* zx   = ws;                               // 19,005,440 f
    float* xh   = zx   + (size_t)ROWS * DINPROJ;    //  8,388,608 f
    float* Bb   = xh   + (size_t)ROWS * DINNER;     //  1,048,576 f
    float* Cb   = Bb   + (size_t)ROWS * DSTATE;     //  1,048,576 f
    float* dtb  = Cb   + (size_t)ROWS * DSTATE;     //    131,072 f
    float* dAb  = dtb  + (size_t)ROWS * NHEADS;     //    131,072 f
    float* yb   = dAb  + (size_t)ROWS * NHEADS;     //  8,388,608 f
    float* UN   = yb   + (size_t)ROWS * DINNER;     // 16,777,216 f (union)
    float* BtF  = UN   + (size_t)16777216;          //  1,245,184 f
    float* WtF  = BtF  + (size_t)1245184;           //    524,288 f
    float* ptot = WtF  + (size_t)524288;            //      2,048 f

    unsigned short* Ah = (unsigned short*)UN;                 // [8192][512]
    unsigned short* Al = Ah + (size_t)ROWS * DMODEL;
    float*          hloc = UN;                                // 16.78M f
    unsigned short* yh = (unsigned short*)UN;                 // [8192][1024]
    unsigned short* yl = yh + (size_t)ROWS * DINNER;

    unsigned short* Bth = (unsigned short*)BtF;               // [2432][512]
    unsigned short* Btl = Bth + (size_t)NPAD_IN * DMODEL;
    unsigned short* Wth = (unsigned short*)WtF;               // [512][1024]
    unsigned short* Wtl = Wth + (size_t)DMODEL * DINNER;

    for (int layer = 0; layer < 2; ++layer) {
        const float* xl = (layer == 0) ? x_in : out;

        split_a_kernel<<<(ROWS * DMODEL) / (256 * 8), 256, 0, stream>>>(xl, Ah, Al);

        tsplit_w_kernel<<<dim3(NPAD_IN / 32, DMODEL / 32), 256, 0, stream>>>(
            in_w + (size_t)layer * DMODEL * DINPROJ, DMODEL, DINPROJ, Bth, Btl);

        gemm_bf16s<<<dim3(NPAD_IN / 128, ROWS / 128), 256, 0, stream>>>(
            Ah, Al, Bth, Btl, zx, DINPROJ, DINPROJ, DMODEL);

        conv_kernel<<<ROWS, CONVDIM / 4, 0, stream>>>(
            zx,
            conv_w + (size_t)layer * DCONV * CONVDIM,
            conv_b + (size_t)layer * CONVDIM,
            dt_bias + (size_t)layer * NHEADS,
            A_log + (size_t)layer * NHEADS,
            xh, Bb, Cb, dtb, dAb);

        scan_local<<<BATCH * NHEADS * NSEG, 128, 0, stream>>>(
            xh, Bb, dtb, dAb, hloc, ptot);

        combine_kernel<<<BATCH * NHEADS * 8, 256, 0, stream>>>(hloc, ptot);

        scan_full<<<BATCH * NHEADS * NSEG, 128, 0, stream>>>(
            xh, Bb, Cb, dtb, dAb, hloc, yb);

        gate_kernel<<<ROWS, 256, 0, stream>>>(
            yb, xh, D_skip + (size_t)layer * NHEADS,
            zx, norm_w + (size_t)layer * DINNER, yh, yl);

        tsplit_w_kernel<<<dim3(DMODEL / 32, DINNER / 32), 256, 0, stream>>>(
            out_w + (size_t)layer * DINNER * DMODEL, DINNER, DMODEL, Wth, Wtl);

        gemm_bf16s<<<dim3(DMODEL / 128, ROWS / 128), 256, 0, stream>>>(
            yh, yl, Wth, Wtl, out, DMODEL, DMODEL, DINNER);
    }
}

// Round 7
// 708.381 us; speedup vs baseline: 6.2702x; 1.1187x over previous
//
#include <hip/hip_runtime.h>
#include <hip/hip_bf16.h>
#include <cstddef>
#include <cstdint>

// Mamba2 (2 layers). GEMMs via split-bf16 MFMA (C = AhBh + AhBl + AlBh),
// segmented-parallel selective scan (NSEG=32). Scan blocks: 256 threads
// (4 waves = 4 n-quarters), each wave carries TWO heads (B/C broadcasts
// amortized over 2 heads); hs[2][32]/lane; LDS-staged B/C/x (dbuf, CH=4);
// y merged across quarters via LDS (2 barriers/chunk, no atomics).
//
// Workspace unchanged: 226.8 MB (budget: 253 MB proven safe).

#define BATCH 4
#define SEQ   2048
#define DMODEL 512
#define DINNER 1024
#define DSTATE 128
#define HEADDIM 64
#define NHEADS 16
#define DCONV 4
#define CONVDIM 1280
#define DINPROJ 2320
#define NPAD_IN 2432          // 19 * 128
#define ROWS (BATCH * SEQ)    // 8192
#define NSEG 32
#define TSEG 64               // SEQ / NSEG
#define CH 4                  // steps staged per LDS chunk
#define NCH (TSEG / CH)       // 16 chunks per segment

typedef __attribute__((ext_vector_type(8))) short bf16x8;
typedef __attribute__((ext_vector_type(4))) float f32x4;

__device__ __forceinline__ float silu_f(float x) {
    return x * (1.0f / (1.0f + __expf(-x)));
}
__device__ __forceinline__ unsigned short f2bfu(float f) {  // RNE fp32->bf16
    unsigned u = __float_as_uint(f);
    unsigned r = u + 0x7FFFu + ((u >> 16) & 1u);
    return (unsigned short)(r >> 16);
}
__device__ __forceinline__ float bfu2f(unsigned short h) {
    return __uint_as_float(((unsigned)h) << 16);
}

// ---------------------------------------------------------------------------
// Split fp32 A[M*K] -> Ah, Al (bf16). 8 elems/thread.
// ---------------------------------------------------------------------------
__global__ __launch_bounds__(256)
void split_a_kernel(const float* __restrict__ A,
                    unsigned short* __restrict__ Ah,
                    unsigned short* __restrict__ Al)
{
    const size_t i = ((size_t)blockIdx.x * 256 + threadIdx.x) * 8;
    const float4 a = *(const float4*)&A[i];
    const float4 b = *(const float4*)&A[i + 4];
    float v[8] = {a.x, a.y, a.z, a.w, b.x, b.y, b.z, b.w};
    unsigned hv[8], lv[8];
#pragma unroll
    for (int j = 0; j < 8; ++j) {
        hv[j] = f2bfu(v[j]);
        lv[j] = f2bfu(v[j] - bfu2f((unsigned short)hv[j]));
    }
    uint4 ph = make_uint4(hv[0] | (hv[1] << 16), hv[2] | (hv[3] << 16),
                          hv[4] | (hv[5] << 16), hv[6] | (hv[7] << 16));
    uint4 pl = make_uint4(lv[0] | (lv[1] << 16), lv[2] | (lv[3] << 16),
                          lv[4] | (lv[5] << 16), lv[6] | (lv[7] << 16));
    *(uint4*)&Ah[i] = ph;
    *(uint4*)&Al[i] = pl;
}

// ---------------------------------------------------------------------------
// Transpose + split weight W[K][N] fp32 -> Oh/Ol[Npad][K] bf16 (n >= N -> 0).
// ---------------------------------------------------------------------------
__global__ __launch_bounds__(256)
void tsplit_w_kernel(const float* __restrict__ W, int K, int N,
                     unsigned short* __restrict__ Oh,
                     unsigned short* __restrict__ Ol)
{
    __shared__ float tile[32][33];
    const int n0 = blockIdx.x * 32, k0 = blockIdx.y * 32;
    const int c = threadIdx.x & 31, r8 = threadIdx.x >> 5;
    const int n = n0 + c;
#pragma unroll
    for (int i = 0; i < 4; ++i) {
        const int k = r8 + i * 8;
        float v = 0.0f;
        if (n < N) v = W[(size_t)(k0 + k) * N + n];
        tile[c][k] = v;
    }
    __syncthreads();
#pragma unroll
    for (int i = 0; i < 4; ++i) {
        const int nl = r8 + i * 8;
        const float v = tile[nl][c];
        const unsigned short h = f2bfu(v);
        const unsigned short l = f2bfu(v - bfu2f(h));
        const size_t o = (size_t)(n0 + nl) * K + k0 + c;
        Oh[o] = h;
        Ol[o] = l;
    }
}

// ---------------------------------------------------------------------------
// Split-bf16 MFMA GEMM (unchanged, passing).
// ---------------------------------------------------------------------------
__global__ __launch_bounds__(256)
void gemm_bf16s(const unsigned short* __restrict__ Ah,
                const unsigned short* __restrict__ Al,
                const unsigned short* __restrict__ Bh,
                const unsigned short* __restrict__ Bl,
                float* __restrict__ C, int ldc, int N, int K)
{
    __shared__ __align__(16) unsigned short As[2][128 * 32];
    __shared__ __align__(16) unsigned short Bs[2][128 * 32];

    const int tid = threadIdx.x;
    const int w = tid >> 6, lane = tid & 63;
    const int wm = w >> 1, wn = w & 1;
    const int row0 = blockIdx.y * 128, col0 = blockIdx.x * 128;

    const int srow = tid >> 1;
    const int sk   = (tid & 1) * 16;

    const int lr = lane & 15;
    const int lk = (lane >> 4) * 8;

    f32x4 acc[4][4];
#pragma unroll
    for (int i = 0; i < 4; ++i)
#pragma unroll
        for (int j = 0; j < 4; ++j) acc[i][j] = (f32x4){0.f, 0.f, 0.f, 0.f};

    for (int k0 = 0; k0 < K; k0 += 32) {
        const size_t ga = (size_t)(row0 + srow) * K + k0 + sk;
        const size_t gb = (size_t)(col0 + srow) * K + k0 + sk;
        const uint4 vah0 = *(const uint4*)&Ah[ga];
        const uint4 vah1 = *(const uint4*)&Ah[ga + 8];
        const uint4 val0 = *(const uint4*)&Al[ga];
        const uint4 val1 = *(const uint4*)&Al[ga + 8];
        const uint4 vbh0 = *(const uint4*)&Bh[gb];
        const uint4 vbh1 = *(const uint4*)&Bh[gb + 8];
        const uint4 vbl0 = *(const uint4*)&Bl[gb];
        const uint4 vbl1 = *(const uint4*)&Bl[gb + 8];
        __syncthreads();
        const int so = srow * 32 + sk;
        *(uint4*)&As[0][so] = vah0;  *(uint4*)&As[0][so + 8] = vah1;
        *(uint4*)&As[1][so] = val0;  *(uint4*)&As[1][so + 8] = val1;
        *(uint4*)&Bs[0][so] = vbh0;  *(uint4*)&Bs[0][so + 8] = vbh1;
        *(uint4*)&Bs[1][so] = vbl0;  *(uint4*)&Bs[1][so + 8] = vbl1;
        __syncthreads();

        bf16x8 a_h[4], a_l[4], b_h[4], b_l[4];
#pragma unroll
        for (int mt = 0; mt < 4; ++mt) {
            const int r = wm * 64 + mt * 16 + lr;
            a_h[mt] = *(const bf16x8*)&As[0][r * 32 + lk];
            a_l[mt] = *(const bf16x8*)&As[1][r * 32 + lk];
        }
#pragma unroll
        for (int nt = 0; nt < 4; ++nt) {
            const int c = wn * 64 + nt * 16 + lr;
            b_h[nt] = *(const bf16x8*)&Bs[0][c * 32 + lk];
            b_l[nt] = *(const bf16x8*)&Bs[1][c * 32 + lk];
        }
#pragma unroll
        for (int mt = 0; mt < 4; ++mt)
#pragma unroll
            for (int nt = 0; nt < 4; ++nt) {
                acc[mt][nt] = __builtin_amdgcn_mfma_f32_16x16x32_bf16(a_h[mt], b_h[nt], acc[mt][nt], 0, 0, 0);
                acc[mt][nt] = __builtin_amdgcn_mfma_f32_16x16x32_bf16(a_h[mt], b_l[nt], acc[mt][nt], 0, 0, 0);
                acc[mt][nt] = __builtin_amdgcn_mfma_f32_16x16x32_bf16(a_l[mt], b_h[nt], acc[mt][nt], 0, 0, 0);
            }
    }

    const int crow = (lane >> 4) * 4;
#pragma unroll
    for (int mt = 0; mt < 4; ++mt)
#pragma unroll
        for (int nt = 0; nt < 4; ++nt) {
            const int cc = col0 + wn * 64 + nt * 16 + lr;
            if (cc < N) {
#pragma unroll
                for (int r = 0; r < 4; ++r)
                    C[(size_t)(row0 + wm * 64 + mt * 16 + crow + r) * ldc + cc] = acc[mt][nt][r];
            }
        }
}

// ---------------------------------------------------------------------------
// Depthwise causal conv (4 taps) + bias + SiLU + dt/dA precompute.
// ---------------------------------------------------------------------------
__global__ __launch_bounds__(320)
void conv_kernel(const float* __restrict__ zx,
                 const float* __restrict__ cw,
                 const float* __restrict__ cb,
                 const float* __restrict__ dtbias,
                 const float* __restrict__ alog,
                 float* __restrict__ xh,
                 float* __restrict__ Bb,
                 float* __restrict__ Cb,
                 float* __restrict__ dtb,
                 float* __restrict__ dAb)
{
    const int row = blockIdx.x;
    const int l   = row & (SEQ - 1);
    const int c4  = threadIdx.x * 4;

    float4 acc = *(const float4*)&cb[c4];
#pragma unroll
    for (int k = 0; k < DCONV; ++k) {
        const int lk = l - (DCONV - 1) + k;
        if (lk >= 0) {
            const float4 v = *(const float4*)&zx[(size_t)(row - (DCONV - 1) + k) * DINPROJ + DINNER + c4];
            const float4 w = *(const float4*)&cw[k * CONVDIM + c4];
            acc.x = fmaf(v.x, w.x, acc.x);
            acc.y = fmaf(v.y, w.y, acc.y);
            acc.z = fmaf(v.z, w.z, acc.z);
            acc.w = fmaf(v.w, w.w, acc.w);
        }
    }
    acc.x = silu_f(acc.x);
    acc.y = silu_f(acc.y);
    acc.z = silu_f(acc.z);
    acc.w = silu_f(acc.w);

    if (c4 < DINNER) {
        *(float4*)&xh[(size_t)row * DINNER + c4] = acc;
    } else if (c4 < DINNER + DSTATE) {
        *(float4*)&Bb[(size_t)row * DSTATE + (c4 - DINNER)] = acc;
    } else {
        *(float4*)&Cb[(size_t)row * DSTATE + (c4 - DINNER - DSTATE)] = acc;
    }

    if (threadIdx.x < NHEADS) {
        const int hh = threadIdx.x;
        const float raw = zx[(size_t)row * DINPROJ + (DINNER + CONVDIM) + hh] + dtbias[hh];
        const float dtv = (raw > 20.0f) ? raw : log1pf(expf(raw));
        const float a = expf(alog[hh]);
        dtb[row * NHEADS + hh] = dtv;
        dAb[row * NHEADS + hh] = expf(-a * dtv);
    }
}

// ---------------------------------------------------------------------------
// Pass 1: local scan per (b,hp,seg): 256 thr (4 waves = n-quarters), 2 heads
// per wave, hs[2][32]/lane, h0 = 0. B/x LDS double-buffered (CH=4).
// ---------------------------------------------------------------------------
__global__ __launch_bounds__(256)
void scan_local(const float* __restrict__ xh,
                const float* __restrict__ Bb,
                const float* __restrict__ dtb,
                const float* __restrict__ dAb,
                float* __restrict__ hloc,   // (b,h,seg) x (128n x 64p)
                float* __restrict__ ptot)   // (b,h,seg)
{
    const int bid  = blockIdx.x;
    const int seg  = bid & (NSEG - 1);
    const int hp   = (bid >> 5) & 7;
    const int b    = bid >> 8;
    const int tid  = threadIdx.x;
    const int q    = tid >> 6;
    const int lane = tid & 63;

    __shared__ __align__(16) float Bs[2][CH * 128];
    __shared__ __align__(16) float xs[2][CH * 128];   // [ts][e*64+p]
    __shared__ float dAs[2][CH * 2];
    __shared__ float dts[2][CH * 2];

    float hsA[32], hsB[32];
#pragma unroll
    for (int j = 0; j < 32; ++j) { hsA[j] = 0.0f; hsB[j] = 0.0f; }
    float pr0 = 1.0f, pr1 = 1.0f;

    const size_t row0 = (size_t)b * SEQ + (size_t)seg * TSEG;
    const float* __restrict__ Bp = Bb + row0 * DSTATE;
    const float* __restrict__ xp = xh + row0 * DINNER + hp * 128;

    const int t2 = tid - 128;
    float4 rb, rx;
    float rsc = 0.0f;

    // prefetch chunk 0
    if (tid < 128) {
        rb = *(const float4*)&Bp[(size_t)(tid >> 5) * DSTATE + (tid & 31) * 4];
    } else {
        rx = *(const float4*)&xp[(size_t)(t2 >> 5) * DINNER + (t2 & 31) * 4];
        if (t2 < 8)
            rsc = dAb[(row0 + (t2 >> 1)) * NHEADS + hp * 2 + (t2 & 1)];
        else if (t2 < 16)
            rsc = dtb[(row0 + ((t2 - 8) >> 1)) * NHEADS + hp * 2 + (t2 & 1)];
    }

    for (int c = 0; c < NCH; ++c) {
        const int cur = c & 1;
        if (tid < 128) {
            *(float4*)&Bs[cur][(tid >> 5) * 128 + (tid & 31) * 4] = rb;
        } else {
            *(float4*)&xs[cur][(t2 >> 5) * 128 + (t2 & 31) * 4] = rx;
            if (t2 < 8)       dAs[cur][t2] = rsc;
            else if (t2 < 16) dts[cur][t2 - 8] = rsc;
        }
        __syncthreads();

        if (c + 1 < NCH) {
            const int t0 = (c + 1) * CH;
            if (tid < 128) {
                rb = *(const float4*)&Bp[(size_t)(t0 + (tid >> 5)) * DSTATE + (tid & 31) * 4];
            } else {
                rx = *(const float4*)&xp[(size_t)(t0 + (t2 >> 5)) * DINNER + (t2 & 31) * 4];
                if (t2 < 8)
                    rsc = dAb[(row0 + t0 + (t2 >> 1)) * NHEADS + hp * 2 + (t2 & 1)];
                else if (t2 < 16)
                    rsc = dtb[(row0 + t0 + ((t2 - 8) >> 1)) * NHEADS + hp * 2 + (t2 & 1)];
            }
        }

#pragma unroll
        for (int ts = 0; ts < CH; ++ts) {
            const float dA0 = dAs[cur][ts * 2 + 0];
            const float dA1 = dAs[cur][ts * 2 + 1];
            const float dtx0 = dts[cur][ts * 2 + 0] * xs[cur][ts * 128 + lane];
            const float dtx1 = dts[cur][ts * 2 + 1] * xs[cur][ts * 128 + 64 + lane];
            pr0 *= dA0;
            pr1 *= dA1;
#pragma unroll
            for (int j4 = 0; j4 < 8; ++j4) {
                const float4 b4 = *(const float4*)&Bs[cur][ts * 128 + q * 32 + j4 * 4];
#pragma unroll
                for (int k = 0; k < 4; ++k) {
                    const float bv = (&b4.x)[k];
                    hsA[j4 * 4 + k] = fmaf(dA0, hsA[j4 * 4 + k], dtx0 * bv);
                    hsB[j4 * 4 + k] = fmaf(dA1, hsB[j4 * 4 + k], dtx1 * bv);
                }
            }
        }
        __syncthreads();
    }

    const size_t sA = ((size_t)(b * NHEADS + hp * 2 + 0) * NSEG + seg) * (DSTATE * HEADDIM);
    const size_t sB = ((size_t)(b * NHEADS + hp * 2 + 1) * NSEG + seg) * (DSTATE * HEADDIM);
#pragma unroll
    for (int j = 0; j < 32; ++j) {
        hloc[sA + (size_t)(q * 32 + j) * HEADDIM + lane] = hsA[j];
        hloc[sB + (size_t)(q * 32 + j) * HEADDIM + lane] = hsB[j];
    }
    if (tid == 0) {
        ptot[(b * NHEADS + hp * 2 + 0) * NSEG + seg] = pr0;
        ptot[(b * NHEADS + hp * 2 + 1) * NSEG + seg] = pr1;
    }
}

// ---------------------------------------------------------------------------
// Pass 2: sequential combine over 32 segments (in-place: hloc becomes h0).
// ---------------------------------------------------------------------------
__global__ __launch_bounds__(256)
void combine_kernel(float* __restrict__ hloc,
                    const float* __restrict__ ptot)
{
    const int bid = blockIdx.x;
    const int bh = bid >> 3;
    const int chunk = bid & 7;
    const int e0 = chunk * 1024 + threadIdx.x * 4;

    float4 s = make_float4(0.f, 0.f, 0.f, 0.f);
    for (int k = 0; k < NSEG; ++k) {
        float* p = &hloc[((size_t)bh * NSEG + k) * (DSTATE * HEADDIM) + e0];
        const float4 v = *(const float4*)p;
        *(float4*)p = s;
        const float pt = ptot[bh * NSEG + k];
        s.x = fmaf(pt, s.x, v.x);
        s.y = fmaf(pt, s.y, v.y);
        s.z = fmaf(pt, s.z, v.z);
        s.w = fmaf(pt, s.w, v.w);
    }
}

// ---------------------------------------------------------------------------
// Pass 3: full scan per (b,hp,seg), true h0. 4 waves = n-quarters, 2 heads
// per wave; y merged across quarters via LDS (2 barriers/chunk).
// ---------------------------------------------------------------------------
__global__ __launch_bounds__(256)
void scan_full(const float* __restrict__ xh,
               const float* __restrict__ Bb,
               const float* __restrict__ Cb,
               const float* __restrict__ dtb,
               const float* __restrict__ dAb,
               const float* __restrict__ h0,    // (b,h,seg) x (128n x 64p)
               float* __restrict__ yb)          // (rows, 1024)
{
    const int bid  = blockIdx.x;
    const int seg  = bid & (NSEG - 1);
    const int hp   = (bid >> 5) & 7;
    const int b    = bid >> 8;
    const int tid  = threadIdx.x;
    const int q    = tid >> 6;
    const int lane = tid & 63;

    __shared__ __align__(16) float Bs[2][CH * 128];
    __shared__ __align__(16) float Cs[2][CH * 128];
    __shared__ __align__(16) float xs[2][CH * 128];     // [ts][e*64+p]
    __shared__ __align__(16) float ys[4][2][CH * 64];   // [q][e][ts*64+p]
    __shared__ float dAs[2][CH * 2];
    __shared__ float dts[2][CH * 2];

    const size_t sA = ((size_t)(b * NHEADS + hp * 2 + 0) * NSEG + seg) * (DSTATE * HEADDIM);
    const size_t sB = ((size_t)(b * NHEADS + hp * 2 + 1) * NSEG + seg) * (DSTATE * HEADDIM);
    float hsA[32], hsB[32];
#pragma unroll
    for (int j = 0; j < 32; ++j) {
        hsA[j] = h0[sA + (size_t)(q * 32 + j) * HEADDIM + lane];
        hsB[j] = h0[sB + (size_t)(q * 32 + j) * HEADDIM + lane];
    }

    const size_t row0 = (size_t)b * SEQ + (size_t)seg * TSEG;
    const float* __restrict__ Bp = Bb + row0 * DSTATE;
    const float* __restrict__ Cp = Cb + row0 * DSTATE;
    const float* __restrict__ xp = xh + row0 * DINNER + hp * 128;
    float* __restrict__ yo = yb + row0 * DINNER + hp * 128;

    const int t2 = tid - 128;
    float4 rb, rc, rx;
    float rsc = 0.0f;

    // prefetch chunk 0
    if (tid < 128) {
        rb = *(const float4*)&Bp[(size_t)(tid >> 5) * DSTATE + (tid & 31) * 4];
        rx = *(const float4*)&xp[(size_t)(tid >> 5) * DINNER + (tid & 31) * 4];
    } else {
        rc = *(const float4*)&Cp[(size_t)(t2 >> 5) * DSTATE + (t2 & 31) * 4];
        if (t2 < 8)
            rsc = dAb[(row0 + (t2 >> 1)) * NHEADS + hp * 2 + (t2 & 1)];
        else if (t2 < 16)
            rsc = dtb[(row0 + ((t2 - 8) >> 1)) * NHEADS + hp * 2 + (t2 & 1)];
    }

    for (int c = 0; c < NCH; ++c) {
        const int cur = c & 1;
        if (tid < 128) {
            *(float4*)&Bs[cur][(tid >> 5) * 128 + (tid & 31) * 4] = rb;
            *(float4*)&xs[cur][(tid >> 5) * 128 + (tid & 31) * 4] = rx;
        } else {
            *(float4*)&Cs[cur][(t2 >> 5) * 128 + (t2 & 31) * 4] = rc;
            if (t2 < 8)       dAs[cur][t2] = rsc;
            else if (t2 < 16) dts[cur][t2 - 8] = rsc;
        }
        __syncthreads();                      // [1] staging visible; prev compute done

        // merge-store chunk c-1 (reads ys of all quarters)
        if (c > 0 && tid < 128) {
            const int e  = tid >> 6;
            const int ts = (tid >> 4) & 3;
            const int p4 = (tid & 15) * 4;
            float4 a0 = *(const float4*)&ys[0][e][ts * 64 + p4];
            const float4 a1 = *(const float4*)&ys[1][e][ts * 64 + p4];
            const float4 a2 = *(const float4*)&ys[2][e][ts * 64 + p4];
            const float4 a3 = *(const float4*)&ys[3][e][ts * 64 + p4];
            a0.x += a1.x + a2.x + a3.x;
            a0.y += a1.y + a2.y + a3.y;
            a0.z += a1.z + a2.z + a3.z;
            a0.w += a1.w + a2.w + a3.w;
            *(float4*)&yo[(size_t)((c - 1) * CH + ts) * DINNER + e * 64 + p4] = a0;
        }
        __syncthreads();                      // [2] merges done before ys overwrite

        if (c + 1 < NCH) {
            const int t0 = (c + 1) * CH;
            if (tid < 128) {
                rb = *(const float4*)&Bp[(size_t)(t0 + (tid >> 5)) * DSTATE + (tid & 31) * 4];
                rx = *(const float4*)&xp[(size_t)(t0 + (tid >> 5)) * DINNER + (tid & 31) * 4];
            } else {
                rc = *(const float4*)&Cp[(size_t)(t0 + (t2 >> 5)) * DSTATE + (t2 & 31) * 4];
                if (t2 < 8)
                    rsc = dAb[(row0 + t0 + (t2 >> 1)) * NHEADS + hp * 2 + (t2 & 1)];
                else if (t2 < 16)
                    rsc = dtb[(row0 + t0 + ((t2 - 8) >> 1)) * NHEADS + hp * 2 + (t2 & 1)];
            }
        }

#pragma unroll
        for (int ts = 0; ts < CH; ++ts) {
            const float dA0 = dAs[cur][ts * 2 + 0];
            const float dA1 = dAs[cur][ts * 2 + 1];
            const float dtx0 = dts[cur][ts * 2 + 0] * xs[cur][ts * 128 + lane];
            const float dtx1 = dts[cur][ts * 2 + 1] * xs[cur][ts * 128 + 64 + lane];
            float y00 = 0.f, y01 = 0.f, y02 = 0.f, y03 = 0.f;
            float y10 = 0.f, y11 = 0.f, y12 = 0.f, y13 = 0.f;
#pragma unroll
            for (int j4 = 0; j4 < 8; ++j4) {
                const float4 b4 = *(const float4*)&Bs[cur][ts * 128 + q * 32 + j4 * 4];
                const float4 c4 = *(const float4*)&Cs[cur][ts * 128 + q * 32 + j4 * 4];
                hsA[j4 * 4 + 0] = fmaf(dA0, hsA[j4 * 4 + 0], dtx0 * b4.x);
                hsA[j4 * 4 + 1] = fmaf(dA0, hsA[j4 * 4 + 1], dtx0 * b4.y);
                hsA[j4 * 4 + 2] = fmaf(dA0, hsA[j4 * 4 + 2], dtx0 * b4.z);
                hsA[j4 * 4 + 3] = fmaf(dA0, hsA[j4 * 4 + 3], dtx0 * b4.w);
                y00 = fmaf(hsA[j4 * 4 + 0], c4.x, y00);
                y01 = fmaf(hsA[j4 * 4 + 1], c4.y, y01);
                y02 = fmaf(hsA[j4 * 4 + 2], c4.z, y02);
                y03 = fmaf(hsA[j4 * 4 + 3], c4.w, y03);
                hsB[j4 * 4 + 0] = fmaf(dA1, hsB[j4 * 4 + 0], dtx1 * b4.x);
                hsB[j4 * 4 + 1] = fmaf(dA1, hsB[j4 * 4 + 1], dtx1 * b4.y);
                hsB[j4 * 4 + 2] = fmaf(dA1, hsB[j4 * 4 + 2], dtx1 * b4.z);
                hsB[j4 * 4 + 3] = fmaf(dA1, hsB[j4 * 4 + 3], dtx1 * b4.w);
                y10 = fmaf(hsB[j4 * 4 + 0], c4.x, y10);
                y11 = fmaf(hsB[j4 * 4 + 1], c4.y, y11);
                y12 = fmaf(hsB[j4 * 4 + 2], c4.z, y12);
                y13 = fmaf(hsB[j4 * 4 + 3], c4.w, y13);
            }
            ys[q][0][ts * 64 + lane] = (y00 + y01) + (y02 + y03);
            ys[q][1][ts * 64 + lane] = (y10 + y11) + (y12 + y13);
        }
    }

    __syncthreads();
    if (tid < 128) {   // store last chunk
        const int e  = tid >> 6;
        const int ts = (tid >> 4) & 3;
        const int p4 = (tid & 15) * 4;
        float4 a0 = *(const float4*)&ys[0][e][ts * 64 + p4];
        const float4 a1 = *(const float4*)&ys[1][e][ts * 64 + p4];
        const float4 a2 = *(const float4*)&ys[2][e][ts * 64 + p4];
        const float4 a3 = *(const float4*)&ys[3][e][ts * 64 + p4];
        a0.x += a1.x + a2.x + a3.x;
        a0.y += a1.y + a2.y + a3.y;
        a0.z += a1.z + a2.z + a3.z;
        a0.w += a1.w + a2.w + a3.w;
        *(float4*)&yo[(size_t)((NCH - 1) * CH + ts) * DINNER + e * 64 + p4] = a0;
    }
}

// ---------------------------------------------------------------------------
// Gate + D-skip + RMSNorm; writes ynorm as split-bf16 planes.
// ---------------------------------------------------------------------------
__global__ __launch_bounds__(256)
void gate_kernel(const float* __restrict__ yb,
                 const float* __restrict__ xh,
                 const float* __restrict__ dskip,
                 const float* __restrict__ zx,
                 const float* __restrict__ nw,
                 unsigned short* __restrict__ yh,
                 unsigned short* __restrict__ yl)
{
    const int row = blockIdx.x;
    const int c4 = threadIdx.x * 4;

    float4 y = *(const float4*)&yb[(size_t)row * DINNER + c4];
    const float4 xv = *(const float4*)&xh[(size_t)row * DINNER + c4];
    const float dsk = dskip[c4 >> 6];
    y.x = fmaf(dsk, xv.x, y.x);
    y.y = fmaf(dsk, xv.y, y.y);
    y.z = fmaf(dsk, xv.z, y.z);
    y.w = fmaf(dsk, xv.w, y.w);

    const float4 z = *(const float4*)&zx[(size_t)row * DINPROJ + c4];
    float4 g;
    g.x = y.x * silu_f(z.x);
    g.y = y.y * silu_f(z.y);
    g.z = y.z * silu_f(z.z);
    g.w = y.w * silu_f(z.w);

    float local = g.x * g.x + g.y * g.y + g.z * g.z + g.w * g.w;
#pragma unroll
    for (int m = 32; m >= 1; m >>= 1) local += __shfl_xor(local, m, 64);

    __shared__ float red[4];
    if ((threadIdx.x & 63) == 0) red[threadIdx.x >> 6] = local;
    __syncthreads();
    const float total = red[0] + red[1] + red[2] + red[3];
    const float scale = rsqrtf(total * (1.0f / (float)DINNER) + 1e-5f);

    const float4 w = *(const float4*)&nw[c4];
    float o[4];
    o[0] = g.x * scale * w.x;
    o[1] = g.y * scale * w.y;
    o[2] = g.z * scale * w.z;
    o[3] = g.w * scale * w.w;

    unsigned hv[4], lv[4];
#pragma unroll
    for (int j = 0; j < 4; ++j) {
        hv[j] = f2bfu(o[j]);
        lv[j] = f2bfu(o[j] - bfu2f((unsigned short)hv[j]));
    }
    const size_t oi = (size_t)row * DINNER + c4;
    *(uint2*)&yh[oi] = make_uint2(hv[0] | (hv[1] << 16), hv[2] | (hv[3] << 16));
    *(uint2*)&yl[oi] = make_uint2(lv[0] | (lv[1] << 16), lv[2] | (lv[3] << 16));
}

// ---------------------------------------------------------------------------
extern "C" void kernel_launch(void* const* d_in, const int* in_sizes, int n_in,
                              void* d_out, int out_size, void* d_ws, size_t ws_size,
                              hipStream_t stream)
{
    const float* x_in    = (const float*)d_in[0];
    const float* in_w    = (const float*)d_in[1];
    const float* conv_w  = (const float*)d_in[2];
    const float* conv_b  = (const float*)d_in[3];
    const float* dt_bias = (const float*)d_in[4];
    const float* A_log   = (const float*)d_in[5];
    const float* D_skip  = (const float*)d_in[6];
    const float* norm_w  = (const float*)d_in[7];
    const float* out_w   = (const float*)d_in[8];
    float* out = (float*)d_out;

    float* ws   = (float*)d_ws;
    float* zx   = ws;                               // 19,005,440 f
    float* xh   = zx   + (size_t)ROWS * DINPROJ;    //  8,388,608 f
    float* Bb   = xh   + (size_t)ROWS * DINNER;     //  1,048,576 f
    float* Cb   = Bb   + (size_t)ROWS * DSTATE;     //  1,048,576 f
    float* dtb  = Cb   + (size_t)ROWS * DSTATE;     //    131,072 f
    float* dAb  = dtb  + (size_t)ROWS * NHEADS;     //    131,072 f
    float* yb   = dAb  + (size_t)ROWS * NHEADS;     //  8,388,608 f
    float* UN   = yb   + (size_t)ROWS * DINNER;     // 16,777,216 f (union)
    float* BtF  = UN   + (size_t)16777216;          //  1,245,184 f
    float* WtF  = BtF  + (size_t)1245184;           //    524,288 f
    float* ptot = WtF  + (size_t)524288;            //      2,048 f

    unsigned short* Ah = (unsigned short*)UN;                 // [8192][512]
    unsigned short* Al = Ah + (size_t)ROWS * DMODEL;
    float*          hloc = UN;                                // 16.78M f
    unsigned short* yh = (unsigned short*)UN;                 // [8192][1024]
    unsigned short* yl = yh + (size_t)ROWS * DINNER;

    unsigned short* Bth = (unsigned short*)BtF;               // [2432][512]
    unsigned short* Btl = Bth + (size_t)NPAD_IN * DMODEL;
    unsigned short* Wth = (unsigned short*)WtF;               // [512][1024]
    unsigned short* Wtl = Wth + (size_t)DMODEL * DINNER;

    for (int layer = 0; layer < 2; ++layer) {
        const float* xl = (layer == 0) ? x_in : out;

        split_a_kernel<<<(ROWS * DMODEL) / (256 * 8), 256, 0, stream>>>(xl, Ah, Al);

        tsplit_w_kernel<<<dim3(NPAD_IN / 32, DMODEL / 32), 256, 0, stream>>>(
            in_w + (size_t)layer * DMODEL * DINPROJ, DMODEL, DINPROJ, Bth, Btl);

        gemm_bf16s<<<dim3(NPAD_IN / 128, ROWS / 128), 256, 0, stream>>>(
            Ah, Al, Bth, Btl, zx, DINPROJ, DINPROJ, DMODEL);

        conv_kernel<<<ROWS, CONVDIM / 4, 0, stream>>>(
            zx,
            conv_w + (size_t)layer * DCONV * CONVDIM,
            conv_b + (size_t)layer * CONVDIM,
            dt_bias + (size_t)layer * NHEADS,
            A_log + (size_t)layer * NHEADS,
            xh, Bb, Cb, dtb, dAb);

        scan_local<<<BATCH * (NHEADS / 2) * NSEG, 256, 0, stream>>>(
            xh, Bb, dtb, dAb, hloc, ptot);

        combine_kernel<<<BATCH * NHEADS * 8, 256, 0, stream>>>(hloc, ptot);

        scan_full<<<BATCH * (NHEADS / 2) * NSEG, 256, 0, stream>>>(
            xh, Bb, Cb, dtb, dAb, hloc, yb);

        gate_kernel<<<ROWS, 256, 0, stream>>>(
            yb, xh, D_skip + (size_t)layer * NHEADS,
            zx, norm_w + (size_t)layer * DINNER, yh, yl);

        tsplit_w_kernel<<<dim3(DMODEL / 32, DINNER / 32), 256, 0, stream>>>(
            out_w + (size_t)layer * DINNER * DMODEL, DINNER, DMODEL, Wth, Wtl);

        gemm_bf16s<<<dim3(DMODEL / 128, ROWS / 128), 256, 0, stream>>>(
            yh, yl, Wth, Wtl, out, DMODEL, DMODEL, DINNER);
    }
}